// Round 16
// baseline (217.686 us; speedup 1.0000x reference)
//
#include <hip/hip_runtime.h>
#include <hip/hip_bf16.h>

typedef __attribute__((ext_vector_type(8))) short short8;
typedef __attribute__((ext_vector_type(4))) float f32x4;
typedef __attribute__((ext_vector_type(16))) float f32x16;
typedef __attribute__((ext_vector_type(4))) unsigned int u32x4;

#define DEV static __device__ __forceinline__

// hardware bf16 convert (RNE, lowers to v_cvt_pk_bf16_f32)
DEV unsigned short bfc(float f) {
    __bf16 h = (__bf16)f;
    return __builtin_bit_cast(unsigned short, h);
}

DEV unsigned int pack2bf(float lo, float hi) {
    return (unsigned int)bfc(lo) | ((unsigned int)bfc(hi) << 16);
}

DEV void gload16(const void* g, void* l) {
    __builtin_amdgcn_global_load_lds(
        (const __attribute__((address_space(1))) unsigned int*)g,
        (__attribute__((address_space(3))) unsigned int*)l, 16, 0, 0);
}

// ---------------- elementwise f32 -> bf16 ----------------
__global__ void cvt_bf16_kernel(const float* __restrict__ in,
                                unsigned short* __restrict__ out, int n4) {
    int stride = gridDim.x * blockDim.x;
    for (int i = blockIdx.x * blockDim.x + threadIdx.x; i < n4; i += stride) {
        float4 v = reinterpret_cast<const float4*>(in)[i];
        ushort4 o;
        o.x = bfc(v.x); o.y = bfc(v.y); o.z = bfc(v.z); o.w = bfc(v.w);
        reinterpret_cast<ushort4*>(out)[i] = o;
    }
}

// ---------------- W [K][N] f32 -> W^T [N][K] bf16 ----------------
__global__ void transpose_cvt_kernel(const float* __restrict__ in,
                                     unsigned short* __restrict__ out,
                                     int K, int N) {
    __shared__ float tile[32][33];
    int n0 = blockIdx.x * 32, k0 = blockIdx.y * 32;
    int tx = threadIdx.x & 31, ty = threadIdx.x >> 5; // 32 x 8
    #pragma unroll
    for (int i = 0; i < 32; i += 8)
        tile[ty + i][tx] = in[(size_t)(k0 + ty + i) * N + n0 + tx];
    __syncthreads();
    #pragma unroll
    for (int i = 0; i < 32; i += 8)
        out[(size_t)(n0 + ty + i) * K + k0 + tx] = bfc(tile[tx][ty + i]);
}

// ---------------- bf16 GEMM: C[M,N] = A[M,K] * Bt[N,K]^T + bias ----------------
// EPI 0: scatter to Q (pre-scaled by log2e/sqrt(64)), K [BH,T,64], Vt [BH,64,T].
// EPI 1: fp32 out [M,N].
template <int EPI>
__global__ __launch_bounds__(256) void gemm_bt(
    const unsigned short* __restrict__ A,
    const unsigned short* __restrict__ Bt,
    const float* __restrict__ bias,
    unsigned short* __restrict__ oQ,
    unsigned short* __restrict__ oK,
    unsigned short* __restrict__ oVt,
    float* __restrict__ oP,
    int M, int N, int K) {
    __shared__ unsigned short As[128 * 32];
    __shared__ unsigned short Bs[128 * 32];
    const int tid = threadIdx.x;
    const int wid = tid >> 6, lane = tid & 63;
    const int r = lane & 15, g = lane >> 4;
    const int wm = wid >> 1, wn = wid & 1;
    const int bm = blockIdx.x, bn = blockIdx.y;

    f32x4 acc[4][4];
    #pragma unroll
    for (int i = 0; i < 4; i++)
        #pragma unroll
        for (int j = 0; j < 4; j++) acc[i][j] = (f32x4)(0.f);

    const int nk = K >> 5;
    for (int kt = 0; kt < nk; ++kt) {
        const int k0 = kt << 5;
        __syncthreads();
        #pragma unroll
        for (int it = 0; it < 2; ++it) {
            int c = it * 256 + wid * 64 + lane;
            int row = c >> 2, cc = c & 3;
            int ccs = cc ^ ((row >> 1) & 3);
            gload16(A + (size_t)(bm * 128 + row) * K + k0 + ccs * 8,
                    (char*)As + (it * 256 + wid * 64) * 16);
            gload16(Bt + (size_t)(bn * 128 + row) * K + k0 + ccs * 8,
                    (char*)Bs + (it * 256 + wid * 64) * 16);
        }
        __syncthreads();
        short8 af[4], bfr[4];
        #pragma unroll
        for (int mi = 0; mi < 4; ++mi) {
            int row = wm * 64 + mi * 16 + r;
            af[mi] = *(const short8*)((const char*)As + row * 64 +
                                      ((g ^ ((row >> 1) & 3)) << 4));
        }
        #pragma unroll
        for (int ni = 0; ni < 4; ++ni) {
            int row = wn * 64 + ni * 16 + r;
            bfr[ni] = *(const short8*)((const char*)Bs + row * 64 +
                                       ((g ^ ((row >> 1) & 3)) << 4));
        }
        #pragma unroll
        for (int mi = 0; mi < 4; ++mi)
            #pragma unroll
            for (int ni = 0; ni < 4; ++ni)
                acc[mi][ni] = __builtin_amdgcn_mfma_f32_16x16x32_bf16(
                    af[mi], bfr[ni], acc[mi][ni], 0, 0, 0);
    }

    const float QSCALE = 0.18033688011112042f; // log2(e)/sqrt(64); exp2 domain
    #pragma unroll
    for (int ni = 0; ni < 4; ++ni) {
        int n = bn * 128 + wn * 64 + ni * 16 + r;
        float bb = bias[n];
        #pragma unroll
        for (int mi = 0; mi < 4; ++mi) {
            #pragma unroll
            for (int rr = 0; rr < 4; ++rr) {
                int m = bm * 128 + wm * 64 + mi * 16 + g * 4 + rr;
                float v = acc[mi][ni][rr] + bb;
                if (EPI == 0) {
                    int b = m >> 11, t = m & 2047;
                    int s = n >> 10, hh = (n >> 6) & 15, dh = n & 63;
                    size_t bh = (size_t)(b * 16 + hh);
                    if (s == 0)      oQ[(bh * 2048 + t) * 64 + dh] = bfc(v * QSCALE);
                    else if (s == 1) oK[(bh * 2048 + t) * 64 + dh] = bfc(v);
                    else             oVt[(bh * 64 + dh) * 2048 + t] = bfc(v);
                } else {
                    oP[(size_t)m * N + n] = v;
                }
            }
        }
    }
}

// ---------------- causal flash attention, swapped-QK 32x32 MFMA ----------------
// Q (pre-scaled, exp2 domain): [BH][2048][64] bf16 ; Kb same ; Vt: [BH][64][2048]
// O: [B][2048][1024] bf16.
// Block: 128 q-rows, 8 waves. Wave pair (w, w+4) shares 32 rows (rg=wid&3);
// pv=wid>>2 picks even/odd 64-key subtile of each staged 128-key tile ->
// every wave does ~half the subtiles; partial (m,l,O) merged at block end
// (exact flash combine via LDS). 1024 blocks vs 512-slot capacity -> backfill;
// LPT dispatch: long strips (s=15..8) first. KVBLK=128 dbuf staging (R15).
__global__ __launch_bounds__(512, 2) void attn_kernel(
    const unsigned short* __restrict__ Q,
    const unsigned short* __restrict__ Kb,
    const unsigned short* __restrict__ Vt,
    unsigned short* __restrict__ O) {
    __shared__ f32x4 ldsraw[4096];                        // 64KB, 16B-aligned
    unsigned short* Ks = (unsigned short*)ldsraw;         // dbuf K: 2 x 16KB
    unsigned short* Vs = (unsigned short*)ldsraw + 16384; // dbuf V: 2 x 16KB
    const int tid = threadIdx.x, wid = tid >> 6, lane = tid & 63;
    const int ln31 = lane & 31, hi = lane >> 5;
    const int rg = wid & 3, pv = wid >> 2;

    // ---- LPT remap: dispatch order l = by*16+bx; long strips first ----
    const int l = blockIdx.y * 16 + blockIdx.x;
    const int i = l & 511;
    const int g = i >> 6;
    const int bh = i & 63;
    const int s = (l < 512) ? (15 - g) : (7 - g); // 128-row strip index [0,16)

    const size_t hoff = (size_t)bh * 2048 * 64;
    const int qrow0 = s * 128 + rg * 32;     // this wave's first q row
    const int tq = qrow0 + ln31;             // this lane's q row
    const float NEG_INF = -__builtin_inff();

    // Q B-fragments: lane(q=ln31, hi): k = st*16 + hi*8 + e
    short8 qf[4];
    #pragma unroll
    for (int st = 0; st < 4; ++st)
        qf[st] = *(const short8*)(Q + hoff + (size_t)tq * 64 + st * 16 + hi * 8);

    f32x16 oacc[2];
    oacc[0] = (f32x16)(0.f); oacc[1] = (f32x16)(0.f);
    float mrow = NEG_INF, lrow = 0.f;

    const unsigned short* Kh = Kb + hoff;
    const unsigned short* Vh = Vt + hoff;

    auto stage = [&](int buf, int kvb) {
        // 128-key tile: K = 1024 chunks (8/row), V = 1024 chunks (16/row);
        // 512 threads x 2 chunks each per matrix.
        #pragma unroll
        for (int it = 0; it < 2; ++it) {
            int c = it * 512 + tid;            // [0,1024)
            int krow = c >> 3, kcc = c & 7;
            int kccs = kcc ^ (krow & 7);
            gload16(Kh + (size_t)(kvb + krow) * 64 + kccs * 8,
                    (char*)Ks + buf * 16384 + c * 16);
            int vrow = c >> 4, vcc = c & 15;
            int vccs = vcc ^ (vrow & 15);
            gload16(Vh + (size_t)vrow * 2048 + kvb + vccs * 8,
                    (char*)Vs + buf * 16384 + c * 16);
        }
    };

    const int nkv = s + 1; // 128-key staged tiles
    stage(0, 0);
    for (int kv = 0; kv < nkv; ++kv) {
        const int kvb = kv * 128;
        const int cur = kv & 1;
        __syncthreads(); // drains stage(cur)'s vmcnt; fences prior reads of buf cur
        if (kv + 1 < nkv) stage(cur ^ 1, kvb + 128);

        const int kvs = kvb + pv * 64; // this wave's 64-key subtile
        if (kvs <= qrow0) {            // wave-uniform: has unmasked keys
            const char* Kbase = (const char*)Ks + cur * 16384;
            const char* Vbase = (const char*)Vs + cur * 16384;
            // ---- S^T = K Q^T : [64 keys x 32 q], two 32-key subtiles ----
            f32x16 s0 = (f32x16)(0.f), s1 = (f32x16)(0.f);
            __builtin_amdgcn_s_setprio(1);
            #pragma unroll
            for (int st = 0; st < 4; ++st) {
                int row0 = pv * 64 + ln31, row1 = pv * 64 + 32 + ln31;
                short8 kf0 = *(const short8*)(Kbase + row0 * 128 +
                                              (((2 * st + hi) ^ (row0 & 7)) << 4));
                short8 kf1 = *(const short8*)(Kbase + row1 * 128 +
                                              (((2 * st + hi) ^ (row1 & 7)) << 4));
                s0 = __builtin_amdgcn_mfma_f32_32x32x16_bf16(kf0, qf[st], s0, 0, 0, 0);
                s1 = __builtin_amdgcn_mfma_f32_32x32x16_bf16(kf1, qf[st], s1, 0, 0, 0);
            }
            __builtin_amdgcn_s_setprio(0);

            // ---- V fragments from LDS, issued BEFORE softmax ----
            short8 vf[4][2];
            #pragma unroll
            for (int m = 0; m < 4; ++m)
                #pragma unroll
                for (int d = 0; d < 2; ++d) {
                    int row = d * 32 + ln31; // dh
                    int slot = (pv * 8 + 2 * m + hi) ^ (row & 15);
                    vf[m][d] = *(const short8*)(Vbase + row * 256 + (slot << 4));
                }

            // ---- causal mask (S pre-scaled via Q, exp2 domain) ----
            if (kvs + 63 > qrow0) {
                const int lim = tq - kvs;
                #pragma unroll
                for (int j = 0; j < 16; ++j) {
                    int krel = (j & 3) + 8 * (j >> 2) + 4 * hi;
                    if (krel > lim)      s0[j] = NEG_INF;
                    if (krel + 32 > lim) s1[j] = NEG_INF;
                }
            }
            // ---- online softmax (exp2 domain; 4-way interleaved chains) ----
            float ma = fmaxf(s0[0], s0[1]), mb = fmaxf(s0[2], s0[3]);
            float mc = fmaxf(s1[0], s1[1]), md = fmaxf(s1[2], s1[3]);
            #pragma unroll
            for (int j = 4; j < 16; j += 4) {
                ma = fmaxf(ma, fmaxf(s0[j], s0[j+1]));
                mb = fmaxf(mb, fmaxf(s0[j+2], s0[j+3]));
                mc = fmaxf(mc, fmaxf(s1[j], s1[j+1]));
                md = fmaxf(md, fmaxf(s1[j+2], s1[j+3]));
            }
            float mloc = fmaxf(fmaxf(ma, mb), fmaxf(mc, md));
            mloc = fmaxf(mloc, __shfl_xor(mloc, 32));
            float mnew = fmaxf(mrow, mloc);
            // bit-exact skip: when all lanes have mloc<=mrow, alpha==1.0 exactly
            if (!__all(mloc <= mrow)) {
                float alpha = exp2f(mrow - mnew);
                lrow *= alpha;
                #pragma unroll
                for (int j = 0; j < 16; ++j) { oacc[0][j] *= alpha; oacc[1][j] *= alpha; }
            }
            mrow = mnew;
            float la = 0.f, lb = 0.f, lc = 0.f, ld = 0.f;
            #pragma unroll
            for (int j = 0; j < 16; j += 2) {
                float p00 = exp2f(s0[j] - mnew), p01 = exp2f(s0[j+1] - mnew);
                float p10 = exp2f(s1[j] - mnew), p11 = exp2f(s1[j+1] - mnew);
                s0[j] = p00; s0[j+1] = p01; s1[j] = p10; s1[j+1] = p11;
                la += p00; lb += p01; lc += p10; ld += p11;
            }
            float ls = (la + lb) + (lc + ld);
            ls += __shfl_xor(ls, 32);
            lrow += ls;

            // ---- O^T += V^T P^T : per k-step m (16 keys), per dh-tile d ----
            __builtin_amdgcn_s_setprio(1);
            #pragma unroll
            for (int m = 0; m < 4; ++m) {
                const int h = m & 1;
                float pa0, pa1, pb0, pb1, pc0, pc1, pd0, pd1;
                if (m < 2) {
                    pa0 = s0[8*h+0]; pa1 = s0[8*h+1]; pc0 = s0[8*h+2]; pc1 = s0[8*h+3];
                    pb0 = s0[8*h+4]; pb1 = s0[8*h+5]; pd0 = s0[8*h+6]; pd1 = s0[8*h+7];
                } else {
                    pa0 = s1[8*h+0]; pa1 = s1[8*h+1]; pc0 = s1[8*h+2]; pc1 = s1[8*h+3];
                    pb0 = s1[8*h+4]; pb1 = s1[8*h+5]; pd0 = s1[8*h+6]; pd1 = s1[8*h+7];
                }
                unsigned int pkA = pack2bf(pa0, pa1), pkC = pack2bf(pc0, pc1);
                unsigned int pkB = pack2bf(pb0, pb1), pkD = pack2bf(pd0, pd1);
                unsigned int oA = __shfl_xor(pkA, 32), oB = __shfl_xor(pkB, 32);
                unsigned int oC = __shfl_xor(pkC, 32), oD = __shfl_xor(pkD, 32);
                u32x4 w;
                w.x = hi ? oB : pkA;  // e0,e1
                w.y = hi ? oD : pkC;  // e2,e3
                w.z = hi ? pkB : oA;  // e4,e5
                w.w = hi ? pkD : oC;  // e6,e7
                short8 pfrag = __builtin_bit_cast(short8, w);
                #pragma unroll
                for (int d = 0; d < 2; ++d)
                    oacc[d] = __builtin_amdgcn_mfma_f32_32x32x16_bf16(vf[m][d], pfrag, oacc[d], 0, 0, 0);
            }
            __builtin_amdgcn_s_setprio(0);
        }
    }

    // ---- pair merge: exact flash combine of (m,l,O) for waves (rg, rg+4) ----
    __syncthreads(); // staging LDS dead; reuse for merge
    float* pb = (float*)ldsraw;
    float* base = pb + (rg * 34) * 64 + lane; // [rg][c][lane], c in [0,34)
    if (pv == 0) {
        base[0] = mrow;
        base[64] = lrow;
        #pragma unroll
        for (int j = 0; j < 16; ++j) {
            base[(2 + j) * 64]  = oacc[0][j];
            base[(18 + j) * 64] = oacc[1][j];
        }
    }
    __syncthreads();
    if (pv == 1) {
        float m1 = base[0], l1 = base[64];
        float m = fmaxf(m1, mrow);
        float a1 = exp2f(m1 - m), a2 = exp2f(mrow - m);
        float linv = 1.0f / (l1 * a1 + lrow * a2);
        float c1 = a1 * linv, c2 = a2 * linv;
        const int b = bh >> 4, h = bh & 15;
        unsigned short* orow = O + (size_t)(b * 2048 + tq) * 1024 + h * 64;
        #pragma unroll
        for (int d = 0; d < 2; ++d)
            #pragma unroll
            for (int u2 = 0; u2 < 4; ++u2) {
                int dh0 = d * 32 + u2 * 8 + 4 * hi;
                float e0 = base[(2 + d * 16 + 4 * u2 + 0) * 64] * c1 + oacc[d][4*u2+0] * c2;
                float e1 = base[(2 + d * 16 + 4 * u2 + 1) * 64] * c1 + oacc[d][4*u2+1] * c2;
                float e2 = base[(2 + d * 16 + 4 * u2 + 2) * 64] * c1 + oacc[d][4*u2+2] * c2;
                float e3 = base[(2 + d * 16 + 4 * u2 + 3) * 64] * c1 + oacc[d][4*u2+3] * c2;
                uint2 w;
                w.x = pack2bf(e0, e1);
                w.y = pack2bf(e2, e3);
                *(uint2*)(orow + dh0) = w;
            }
    }
}

extern "C" void kernel_launch(void* const* d_in, const int* in_sizes, int n_in,
                              void* d_out, int out_size, void* d_ws, size_t ws_size,
                              hipStream_t stream) {
    const float* x     = (const float*)d_in[0];
    const float* Wqkv  = (const float*)d_in[2];
    const float* bqkv  = (const float*)d_in[3];
    const float* Wproj = (const float*)d_in[4];
    const float* bproj = (const float*)d_in[5];
    float* out = (float*)d_out;

    // ws layout (72 MB): Ob aliases xb — xb is dead after gemm<0> (launch 4),
    // Ob is first written by attn (launch 5). Stream order makes this safe.
    char* ws = (char*)d_ws;
    unsigned short* xb  = (unsigned short*)(ws);                    // 16MB [0,16)
    unsigned short* Ob  = (unsigned short*)(ws);                    // alias of xb
    unsigned short* WqT = (unsigned short*)(ws + (16u << 20));      // 6MB  [3072][1024]
    unsigned short* WpT = (unsigned short*)(ws + (22u << 20));      // 2MB  [1024][1024]
    unsigned short* Qb  = (unsigned short*)(ws + (24u << 20));      // 16MB [64][2048][64]
    unsigned short* Kb  = (unsigned short*)(ws + (40u << 20));      // 16MB
    unsigned short* Vt  = (unsigned short*)(ws + (56u << 20));      // 16MB [64][64][2048]

    cvt_bf16_kernel<<<2048, 256, 0, stream>>>(x, xb, (8192 * 1024) / 4);
    transpose_cvt_kernel<<<dim3(96, 32), 256, 0, stream>>>(Wqkv, WqT, 1024, 3072);
    transpose_cvt_kernel<<<dim3(32, 32), 256, 0, stream>>>(Wproj, WpT, 1024, 1024);
    gemm_bt<0><<<dim3(64, 24), 256, 0, stream>>>(xb, WqT, bqkv, Qb, Kb, Vt, nullptr,
                                                 8192, 3072, 1024);
    attn_kernel<<<dim3(16, 64), 512, 0, stream>>>(Qb, Kb, Vt, Ob);
    gemm_bt<1><<<dim3(64, 8), 256, 0, stream>>>(Ob, WpT, bproj, nullptr, nullptr,
                                                nullptr, out, 8192, 1024, 1024);
}

// Round 20
// 210.576 us; speedup vs baseline: 1.0338x; 1.0338x over previous
//
#include <hip/hip_runtime.h>
#include <hip/hip_bf16.h>

typedef __attribute__((ext_vector_type(8))) short short8;
typedef __attribute__((ext_vector_type(4))) float f32x4;
typedef __attribute__((ext_vector_type(16))) float f32x16;
typedef __attribute__((ext_vector_type(4))) unsigned int u32x4;
typedef __attribute__((ext_vector_type(2))) unsigned int u32x2;

#define DEV static __device__ __forceinline__

// hardware bf16 convert (RNE, lowers to v_cvt_pk_bf16_f32)
DEV unsigned short bfc(float f) {
    __bf16 h = (__bf16)f;
    return __builtin_bit_cast(unsigned short, h);
}

DEV unsigned int pack2bf(float lo, float hi) {
    return (unsigned int)bfc(lo) | ((unsigned int)bfc(hi) << 16);
}

DEV void gload16(const void* g, void* l) {
    __builtin_amdgcn_global_load_lds(
        (const __attribute__((address_space(1))) unsigned int*)g,
        (__attribute__((address_space(3))) unsigned int*)l, 16, 0, 0);
}

// ---------------- elementwise f32 -> bf16 ----------------
__global__ void cvt_bf16_kernel(const float* __restrict__ in,
                                unsigned short* __restrict__ out, int n4) {
    int stride = gridDim.x * blockDim.x;
    for (int i = blockIdx.x * blockDim.x + threadIdx.x; i < n4; i += stride) {
        float4 v = reinterpret_cast<const float4*>(in)[i];
        ushort4 o;
        o.x = bfc(v.x); o.y = bfc(v.y); o.z = bfc(v.z); o.w = bfc(v.w);
        reinterpret_cast<ushort4*>(out)[i] = o;
    }
}

// ---------------- W [K][N] f32 -> W^T [N][K] bf16 ----------------
__global__ void transpose_cvt_kernel(const float* __restrict__ in,
                                     unsigned short* __restrict__ out,
                                     int K, int N) {
    __shared__ float tile[32][33];
    int n0 = blockIdx.x * 32, k0 = blockIdx.y * 32;
    int tx = threadIdx.x & 31, ty = threadIdx.x >> 5; // 32 x 8
    #pragma unroll
    for (int i = 0; i < 32; i += 8)
        tile[ty + i][tx] = in[(size_t)(k0 + ty + i) * N + n0 + tx];
    __syncthreads();
    #pragma unroll
    for (int i = 0; i < 32; i += 8)
        out[(size_t)(n0 + ty + i) * K + k0 + tx] = bfc(tile[tx][ty + i]);
}

// ---------------- bf16 GEMM: C[M,N] = A[M,K] * Bt[N,K]^T + bias ----------------
// EPI 0: scatter to Q (pre-scaled by log2e/sqrt(64)), K [BH,T,64], Vt [BH,64,T].
// EPI 1: fp32 out [M,N].
template <int EPI>
__global__ __launch_bounds__(256) void gemm_bt(
    const unsigned short* __restrict__ A,
    const unsigned short* __restrict__ Bt,
    const float* __restrict__ bias,
    unsigned short* __restrict__ oQ,
    unsigned short* __restrict__ oK,
    unsigned short* __restrict__ oVt,
    float* __restrict__ oP,
    int M, int N, int K) {
    __shared__ unsigned short As[128 * 32];
    __shared__ unsigned short Bs[128 * 32];
    const int tid = threadIdx.x;
    const int wid = tid >> 6, lane = tid & 63;
    const int r = lane & 15, g = lane >> 4;
    const int wm = wid >> 1, wn = wid & 1;
    const int bm = blockIdx.x, bn = blockIdx.y;

    f32x4 acc[4][4];
    #pragma unroll
    for (int i = 0; i < 4; i++)
        #pragma unroll
        for (int j = 0; j < 4; j++) acc[i][j] = (f32x4)(0.f);

    const int nk = K >> 5;
    for (int kt = 0; kt < nk; ++kt) {
        const int k0 = kt << 5;
        __syncthreads();
        #pragma unroll
        for (int it = 0; it < 2; ++it) {
            int c = it * 256 + wid * 64 + lane;
            int row = c >> 2, cc = c & 3;
            int ccs = cc ^ ((row >> 1) & 3);
            gload16(A + (size_t)(bm * 128 + row) * K + k0 + ccs * 8,
                    (char*)As + (it * 256 + wid * 64) * 16);
            gload16(Bt + (size_t)(bn * 128 + row) * K + k0 + ccs * 8,
                    (char*)Bs + (it * 256 + wid * 64) * 16);
        }
        __syncthreads();
        short8 af[4], bfr[4];
        #pragma unroll
        for (int mi = 0; mi < 4; ++mi) {
            int row = wm * 64 + mi * 16 + r;
            af[mi] = *(const short8*)((const char*)As + row * 64 +
                                      ((g ^ ((row >> 1) & 3)) << 4));
        }
        #pragma unroll
        for (int ni = 0; ni < 4; ++ni) {
            int row = wn * 64 + ni * 16 + r;
            bfr[ni] = *(const short8*)((const char*)Bs + row * 64 +
                                       ((g ^ ((row >> 1) & 3)) << 4));
        }
        #pragma unroll
        for (int mi = 0; mi < 4; ++mi)
            #pragma unroll
            for (int ni = 0; ni < 4; ++ni)
                acc[mi][ni] = __builtin_amdgcn_mfma_f32_16x16x32_bf16(
                    af[mi], bfr[ni], acc[mi][ni], 0, 0, 0);
    }

    const float QSCALE = 0.18033688011112042f; // log2(e)/sqrt(64); exp2 domain
    #pragma unroll
    for (int ni = 0; ni < 4; ++ni) {
        int n = bn * 128 + wn * 64 + ni * 16 + r;
        float bb = bias[n];
        #pragma unroll
        for (int mi = 0; mi < 4; ++mi) {
            #pragma unroll
            for (int rr = 0; rr < 4; ++rr) {
                int m = bm * 128 + wm * 64 + mi * 16 + g * 4 + rr;
                float v = acc[mi][ni][rr] + bb;
                if (EPI == 0) {
                    int b = m >> 11, t = m & 2047;
                    int s = n >> 10, hh = (n >> 6) & 15, dh = n & 63;
                    size_t bh = (size_t)(b * 16 + hh);
                    if (s == 0)      oQ[(bh * 2048 + t) * 64 + dh] = bfc(v * QSCALE);
                    else if (s == 1) oK[(bh * 2048 + t) * 64 + dh] = bfc(v);
                    else             oVt[(bh * 64 + dh) * 2048 + t] = bfc(v);
                } else {
                    oP[(size_t)m * N + n] = v;
                }
            }
        }
    }
}

// ---------------- causal flash attention, swapped-QK 32x32 MFMA ----------------
// Q (pre-scaled, exp2 domain): [BH][2048][64] bf16 ; Kb same ; Vt: [BH][64][2048]
// O: [B][2048][1024] bf16. 8 waves x 32 q-rows = 256 rows/block (512 thr).
// KVBLK=128 staged per barrier, two sequential 64-key passes (R15-proven best).
// R17 delta: P-fragment exchange via v_permlane32_swap_b32 (T12) — semantics:
// new_a[32:63]=old_b[0:31], new_b[0:31]=old_a[32:63] => r.x[i]=(i<32)?a[i]:b[i-32],
// r.y[i]=(i<32)?a[i+32]:b[i] — exactly the two words the PV B-frag needs.
// Replaces 4 shfl_xor + 4 selects per k-step. Bit-identical values, less VALU.
__global__ __launch_bounds__(512, 2) void attn_kernel(
    const unsigned short* __restrict__ Q,
    const unsigned short* __restrict__ Kb,
    const unsigned short* __restrict__ Vt,
    unsigned short* __restrict__ O) {
    __shared__ unsigned short Ks[2 * 128 * 64]; // dbuf [key][dh], 128B rows, swizzled
    __shared__ unsigned short Vs[2 * 64 * 128]; // dbuf [dh][key], 256B rows, swizzled
    const int tid = threadIdx.x, wid = tid >> 6, lane = tid & 63;
    const int ln31 = lane & 31, hi = lane >> 5;

    // ---- balance remap (512 blocks; dispatch order l = by*8+bx) ----
    const int l = blockIdx.y * 8 + blockIdx.x;
    const int u = l & 255, v = l >> 8;          // v in {0,1}
    const int bh = v * 32 + (u >> 3);           // [0,64)
    const int qt = v ? (7 - (u & 7)) : (u & 7); // [0,8), 256 q rows per qt

    const size_t hoff = (size_t)bh * 2048 * 64;
    const int qrow0 = qt * 256 + wid * 32;   // this wave's first q row
    const int tq = qrow0 + ln31;             // this lane's q row
    const float NEG_INF = -__builtin_inff();

    // Q B-fragments: lane(q=ln31, hi): k = st*16 + hi*8 + e
    short8 qf[4];
    #pragma unroll
    for (int st = 0; st < 4; ++st)
        qf[st] = *(const short8*)(Q + hoff + (size_t)tq * 64 + st * 16 + hi * 8);

    f32x16 oacc[2];
    oacc[0] = (f32x16)(0.f); oacc[1] = (f32x16)(0.f);
    float mrow = NEG_INF, lrow = 0.f;

    const unsigned short* Kh = Kb + hoff;
    const unsigned short* Vh = Vt + hoff;

    auto stage = [&](int buf, int kvb) {
        // 128-key tile: K = 1024 chunks (8/row), V = 1024 chunks (16/row);
        // 512 threads x 2 chunks each per matrix.
        #pragma unroll
        for (int it = 0; it < 2; ++it) {
            int c = it * 512 + tid;            // [0,1024)
            int krow = c >> 3, kcc = c & 7;
            int kccs = kcc ^ (krow & 7);
            gload16(Kh + (size_t)(kvb + krow) * 64 + kccs * 8,
                    (char*)Ks + buf * 16384 + c * 16);
            int vrow = c >> 4, vcc = c & 15;
            int vccs = vcc ^ (vrow & 15);
            gload16(Vh + (size_t)vrow * 2048 + kvb + vccs * 8,
                    (char*)Vs + buf * 16384 + c * 16);
        }
    };

    const int nkv = 2 * qt + 2; // 128-key tiles
    stage(0, 0);
    for (int kv = 0; kv < nkv; ++kv) {
        const int kvb = kv * 128;
        const int cur = kv & 1;
        __syncthreads(); // drains stage(cur)'s vmcnt; fences prior reads of buf cur
        if (kv + 1 < nkv) stage(cur ^ 1, kvb + 128);

        const char* Kbase = (const char*)Ks + cur * 16384;
        const char* Vbase = (const char*)Vs + cur * 16384;

        #pragma unroll
        for (int sub = 0; sub < 2; ++sub) {
            const int kvs = kvb + sub * 64;
            if (kvs > qrow0) continue; // wave-uniform: no unmasked key in subtile

            // ---- S^T = K Q^T : [64 keys x 32 q], two 32-key subtiles ----
            f32x16 s0 = (f32x16)(0.f), s1 = (f32x16)(0.f);
            __builtin_amdgcn_s_setprio(1);
            #pragma unroll
            for (int st = 0; st < 4; ++st) {
                int row0 = sub * 64 + ln31, row1 = sub * 64 + 32 + ln31;
                short8 kf0 = *(const short8*)(Kbase + row0 * 128 +
                                              (((2 * st + hi) ^ (row0 & 7)) << 4));
                short8 kf1 = *(const short8*)(Kbase + row1 * 128 +
                                              (((2 * st + hi) ^ (row1 & 7)) << 4));
                s0 = __builtin_amdgcn_mfma_f32_32x32x16_bf16(kf0, qf[st], s0, 0, 0, 0);
                s1 = __builtin_amdgcn_mfma_f32_32x32x16_bf16(kf1, qf[st], s1, 0, 0, 0);
            }
            __builtin_amdgcn_s_setprio(0);

            // ---- V fragments from LDS, issued BEFORE softmax (latency hides
            // under the exp/max chain). V rows are 256B, 16 chunks/row ----
            short8 vf[4][2];
            #pragma unroll
            for (int m = 0; m < 4; ++m)
                #pragma unroll
                for (int d = 0; d < 2; ++d) {
                    int row = d * 32 + ln31; // dh
                    int slot = (sub * 8 + 2 * m + hi) ^ (row & 15);
                    vf[m][d] = *(const short8*)(Vbase + row * 256 + (slot << 4));
                }

            // ---- causal mask (S pre-scaled via Q, exp2 domain) ----
            if (kvs + 63 > qrow0) {
                const int lim = tq - kvs;
                #pragma unroll
                for (int j = 0; j < 16; ++j) {
                    int krel = (j & 3) + 8 * (j >> 2) + 4 * hi;
                    if (krel > lim)      s0[j] = NEG_INF;
                    if (krel + 32 > lim) s1[j] = NEG_INF;
                }
            }
            // ---- online softmax (exp2 domain; 4-way interleaved chains) ----
            float ma = fmaxf(s0[0], s0[1]), mb = fmaxf(s0[2], s0[3]);
            float mc = fmaxf(s1[0], s1[1]), md = fmaxf(s1[2], s1[3]);
            #pragma unroll
            for (int j = 4; j < 16; j += 4) {
                ma = fmaxf(ma, fmaxf(s0[j], s0[j+1]));
                mb = fmaxf(mb, fmaxf(s0[j+2], s0[j+3]));
                mc = fmaxf(mc, fmaxf(s1[j], s1[j+1]));
                md = fmaxf(md, fmaxf(s1[j+2], s1[j+3]));
            }
            float mloc = fmaxf(fmaxf(ma, mb), fmaxf(mc, md));
            mloc = fmaxf(mloc, __shfl_xor(mloc, 32));
            float mnew = fmaxf(mrow, mloc);
            // bit-exact skip: when all lanes have mloc<=mrow, alpha==1.0 exactly
            if (!__all(mloc <= mrow)) {
                float alpha = exp2f(mrow - mnew);
                lrow *= alpha;
                #pragma unroll
                for (int j = 0; j < 16; ++j) { oacc[0][j] *= alpha; oacc[1][j] *= alpha; }
            }
            mrow = mnew;
            float la = 0.f, lb = 0.f, lc = 0.f, ld = 0.f;
            #pragma unroll
            for (int j = 0; j < 16; j += 2) {
                float p00 = exp2f(s0[j] - mnew), p01 = exp2f(s0[j+1] - mnew);
                float p10 = exp2f(s1[j] - mnew), p11 = exp2f(s1[j+1] - mnew);
                s0[j] = p00; s0[j+1] = p01; s1[j] = p10; s1[j+1] = p11;
                la += p00; lb += p01; lc += p10; ld += p11;
            }
            float ls = (la + lb) + (lc + ld);
            ls += __shfl_xor(ls, 32);
            lrow += ls;

            // ---- O^T += V^T P^T : per k-step m (16 keys), per dh-tile d ----
            __builtin_amdgcn_s_setprio(1);
            #pragma unroll
            for (int m = 0; m < 4; ++m) {
                const int h = m & 1;
                float pa0, pa1, pb0, pb1, pc0, pc1, pd0, pd1;
                if (m < 2) {
                    pa0 = s0[8*h+0]; pa1 = s0[8*h+1]; pc0 = s0[8*h+2]; pc1 = s0[8*h+3];
                    pb0 = s0[8*h+4]; pb1 = s0[8*h+5]; pd0 = s0[8*h+6]; pd1 = s0[8*h+7];
                } else {
                    pa0 = s1[8*h+0]; pa1 = s1[8*h+1]; pc0 = s1[8*h+2]; pc1 = s1[8*h+3];
                    pb0 = s1[8*h+4]; pb1 = s1[8*h+5]; pd0 = s1[8*h+6]; pd1 = s1[8*h+7];
                }
                unsigned int pkA = pack2bf(pa0, pa1), pkC = pack2bf(pc0, pc1);
                unsigned int pkB = pack2bf(pb0, pb1), pkD = pack2bf(pd0, pd1);
                // permlane32_swap: r.x[i]=(i<32)?a[i]:b[i-32], r.y[i]=(i<32)?a[i+32]:b[i]
                u32x2 rAB = __builtin_amdgcn_permlane32_swap(pkA, pkB, false, false);
                u32x2 rCD = __builtin_amdgcn_permlane32_swap(pkC, pkD, false, false);
                u32x4 w;
                w.x = rAB.x;  // e0,e1
                w.y = rCD.x;  // e2,e3
                w.z = rAB.y;  // e4,e5
                w.w = rCD.y;  // e6,e7
                short8 pfrag = __builtin_bit_cast(short8, w);
                #pragma unroll
                for (int d = 0; d < 2; ++d)
                    oacc[d] = __builtin_amdgcn_mfma_f32_32x32x16_bf16(vf[m][d], pfrag, oacc[d], 0, 0, 0);
            }
            __builtin_amdgcn_s_setprio(0);
        }
    }

    // ---- epilogue: lane writes row t = tq, dh varies ----
    const int b = bh >> 4, h = bh & 15;
    const float rinv = 1.0f / lrow;
    unsigned short* orow = O + (size_t)(b * 2048 + tq) * 1024 + h * 64;
    #pragma unroll
    for (int d = 0; d < 2; ++d)
        #pragma unroll
        for (int u2 = 0; u2 < 4; ++u2) {
            int dh0 = d * 32 + u2 * 8 + 4 * hi;
            uint2 w;
            w.x = pack2bf(oacc[d][4*u2+0] * rinv, oacc[d][4*u2+1] * rinv);
            w.y = pack2bf(oacc[d][4*u2+2] * rinv, oacc[d][4*u2+3] * rinv);
            *(uint2*)(orow + dh0) = w;
        }
}

extern "C" void kernel_launch(void* const* d_in, const int* in_sizes, int n_in,
                              void* d_out, int out_size, void* d_ws, size_t ws_size,
                              hipStream_t stream) {
    const float* x     = (const float*)d_in[0];
    const float* Wqkv  = (const float*)d_in[2];
    const float* bqkv  = (const float*)d_in[3];
    const float* Wproj = (const float*)d_in[4];
    const float* bproj = (const float*)d_in[5];
    float* out = (float*)d_out;

    // ws layout (72 MB): Ob aliases xb — xb is dead after gemm<0> (launch 4),
    // Ob is first written by attn (launch 5). Stream order makes this safe.
    char* ws = (char*)d_ws;
    unsigned short* xb  = (unsigned short*)(ws);                    // 16MB [0,16)
    unsigned short* Ob  = (unsigned short*)(ws);                    // alias of xb
    unsigned short* WqT = (unsigned short*)(ws + (16u << 20));      // 6MB  [3072][1024]
    unsigned short* WpT = (unsigned short*)(ws + (22u << 20));      // 2MB  [1024][1024]
    unsigned short* Qb  = (unsigned short*)(ws + (24u << 20));      // 16MB [64][2048][64]
    unsigned short* Kb  = (unsigned short*)(ws + (40u << 20));      // 16MB
    unsigned short* Vt  = (unsigned short*)(ws + (56u << 20));      // 16MB [64][64][2048]

    cvt_bf16_kernel<<<2048, 256, 0, stream>>>(x, xb, (8192 * 1024) / 4);
    transpose_cvt_kernel<<<dim3(96, 32), 256, 0, stream>>>(Wqkv, WqT, 1024, 3072);
    transpose_cvt_kernel<<<dim3(32, 32), 256, 0, stream>>>(Wproj, WpT, 1024, 1024);
    gemm_bt<0><<<dim3(64, 24), 256, 0, stream>>>(xb, WqT, bqkv, Qb, Kb, Vt, nullptr,
                                                 8192, 3072, 1024);
    attn_kernel<<<dim3(8, 64), 512, 0, stream>>>(Qb, Kb, Vt, Ob);
    gemm_bt<1><<<dim3(64, 8), 256, 0, stream>>>(Ob, WpT, bproj, nullptr, nullptr,
                                                nullptr, out, 8192, 1024, 1024);
}

// Round 21
// 206.859 us; speedup vs baseline: 1.0523x; 1.0180x over previous
//
#include <hip/hip_runtime.h>
#include <hip/hip_bf16.h>

typedef __attribute__((ext_vector_type(8))) short short8;
typedef __attribute__((ext_vector_type(4))) float f32x4;
typedef __attribute__((ext_vector_type(16))) float f32x16;
typedef __attribute__((ext_vector_type(4))) unsigned int u32x4;
typedef __attribute__((ext_vector_type(2))) unsigned int u32x2;

#define DEV static __device__ __forceinline__

// hardware bf16 convert (RNE, lowers to v_cvt_pk_bf16_f32)
DEV unsigned short bfc(float f) {
    __bf16 h = (__bf16)f;
    return __builtin_bit_cast(unsigned short, h);
}

DEV unsigned int pack2bf(float lo, float hi) {
    return (unsigned int)bfc(lo) | ((unsigned int)bfc(hi) << 16);
}

DEV void gload16(const void* g, void* l) {
    __builtin_amdgcn_global_load_lds(
        (const __attribute__((address_space(1))) unsigned int*)g,
        (__attribute__((address_space(3))) unsigned int*)l, 16, 0, 0);
}

// ---------------- elementwise f32 -> bf16 ----------------
__global__ void cvt_bf16_kernel(const float* __restrict__ in,
                                unsigned short* __restrict__ out, int n4) {
    int stride = gridDim.x * blockDim.x;
    for (int i = blockIdx.x * blockDim.x + threadIdx.x; i < n4; i += stride) {
        float4 v = reinterpret_cast<const float4*>(in)[i];
        ushort4 o;
        o.x = bfc(v.x); o.y = bfc(v.y); o.z = bfc(v.z); o.w = bfc(v.w);
        reinterpret_cast<ushort4*>(out)[i] = o;
    }
}

// ---------------- W [K][N] f32 -> W^T [N][K] bf16 ----------------
__global__ void transpose_cvt_kernel(const float* __restrict__ in,
                                     unsigned short* __restrict__ out,
                                     int K, int N) {
    __shared__ float tile[32][33];
    int n0 = blockIdx.x * 32, k0 = blockIdx.y * 32;
    int tx = threadIdx.x & 31, ty = threadIdx.x >> 5; // 32 x 8
    #pragma unroll
    for (int i = 0; i < 32; i += 8)
        tile[ty + i][tx] = in[(size_t)(k0 + ty + i) * N + n0 + tx];
    __syncthreads();
    #pragma unroll
    for (int i = 0; i < 32; i += 8)
        out[(size_t)(n0 + ty + i) * K + k0 + tx] = bfc(tile[tx][ty + i]);
}

// ---------------- bf16 GEMM: C[M,N] = A[M,K] * Bt[N,K]^T + bias ----------------
// EPI 0: scatter to Q (pre-scaled by log2e/sqrt(64)), K [BH,T,64], Vt [BH,64,T].
// EPI 1: fp32 out [M,N].
// R21: 2-phase double-buffered K-loop (attn-proven R10/R15 pattern): one
// barrier per K-step; stage(next) overlaps compute(cur). LDS 16->32KB.
template <int EPI>
__global__ __launch_bounds__(256) void gemm_bt(
    const unsigned short* __restrict__ A,
    const unsigned short* __restrict__ Bt,
    const float* __restrict__ bias,
    unsigned short* __restrict__ oQ,
    unsigned short* __restrict__ oK,
    unsigned short* __restrict__ oVt,
    float* __restrict__ oP,
    int M, int N, int K) {
    __shared__ unsigned short As[2 * 128 * 32]; // dbuf, 8KB per buffer
    __shared__ unsigned short Bs[2 * 128 * 32];
    const int tid = threadIdx.x;
    const int wid = tid >> 6, lane = tid & 63;
    const int r = lane & 15, g = lane >> 4;
    const int wm = wid >> 1, wn = wid & 1;
    const int bm = blockIdx.x, bn = blockIdx.y;

    f32x4 acc[4][4];
    #pragma unroll
    for (int i = 0; i < 4; i++)
        #pragma unroll
        for (int j = 0; j < 4; j++) acc[i][j] = (f32x4)(0.f);

    auto stage = [&](int buf, int k0) {
        #pragma unroll
        for (int it = 0; it < 2; ++it) {
            int c = it * 256 + wid * 64 + lane; // 16B chunk id, 4 chunks/row
            int row = c >> 2, cc = c & 3;
            int ccs = cc ^ ((row >> 1) & 3);    // swizzled source chunk
            gload16(A + (size_t)(bm * 128 + row) * K + k0 + ccs * 8,
                    (char*)As + buf * 8192 + (it * 256 + wid * 64) * 16);
            gload16(Bt + (size_t)(bn * 128 + row) * K + k0 + ccs * 8,
                    (char*)Bs + buf * 8192 + (it * 256 + wid * 64) * 16);
        }
    };

    const int nk = K >> 5;
    stage(0, 0);
    for (int kt = 0; kt < nk; ++kt) {
        const int cur = kt & 1;
        __syncthreads(); // drains stage(cur)'s vmcnt; fences prior reads of buf cur
        if (kt + 1 < nk) stage(cur ^ 1, (kt + 1) << 5);

        const char* Abase = (const char*)As + cur * 8192;
        const char* Bbase = (const char*)Bs + cur * 8192;
        short8 af[4], bfr[4];
        #pragma unroll
        for (int mi = 0; mi < 4; ++mi) {
            int row = wm * 64 + mi * 16 + r;
            af[mi] = *(const short8*)(Abase + row * 64 +
                                      ((g ^ ((row >> 1) & 3)) << 4));
        }
        #pragma unroll
        for (int ni = 0; ni < 4; ++ni) {
            int row = wn * 64 + ni * 16 + r;
            bfr[ni] = *(const short8*)(Bbase + row * 64 +
                                       ((g ^ ((row >> 1) & 3)) << 4));
        }
        __builtin_amdgcn_s_setprio(1);
        #pragma unroll
        for (int mi = 0; mi < 4; ++mi)
            #pragma unroll
            for (int ni = 0; ni < 4; ++ni)
                acc[mi][ni] = __builtin_amdgcn_mfma_f32_16x16x32_bf16(
                    af[mi], bfr[ni], acc[mi][ni], 0, 0, 0);
        __builtin_amdgcn_s_setprio(0);
    }

    const float QSCALE = 0.18033688011112042f; // log2(e)/sqrt(64); exp2 domain
    #pragma unroll
    for (int ni = 0; ni < 4; ++ni) {
        int n = bn * 128 + wn * 64 + ni * 16 + r;
        float bb = bias[n];
        #pragma unroll
        for (int mi = 0; mi < 4; ++mi) {
            #pragma unroll
            for (int rr = 0; rr < 4; ++rr) {
                int m = bm * 128 + wm * 64 + mi * 16 + g * 4 + rr;
                float v = acc[mi][ni][rr] + bb;
                if (EPI == 0) {
                    int b = m >> 11, t = m & 2047;
                    int s = n >> 10, hh = (n >> 6) & 15, dh = n & 63;
                    size_t bh = (size_t)(b * 16 + hh);
                    if (s == 0)      oQ[(bh * 2048 + t) * 64 + dh] = bfc(v * QSCALE);
                    else if (s == 1) oK[(bh * 2048 + t) * 64 + dh] = bfc(v);
                    else             oVt[(bh * 64 + dh) * 2048 + t] = bfc(v);
                } else {
                    oP[(size_t)m * N + n] = v;
                }
            }
        }
    }
}

// ---------------- causal flash attention, swapped-QK 32x32 MFMA ----------------
// Q (pre-scaled, exp2 domain): [BH][2048][64] bf16 ; Kb same ; Vt: [BH][64][2048]
// O: [B][2048][1024] bf16. 8 waves x 32 q-rows = 256 rows/block (512 thr).
// KVBLK=128 staged per barrier, two sequential 64-key passes; permlane32_swap
// P-exchange (R20-verified: 96.6us, bit-exact).
__global__ __launch_bounds__(512, 2) void attn_kernel(
    const unsigned short* __restrict__ Q,
    const unsigned short* __restrict__ Kb,
    const unsigned short* __restrict__ Vt,
    unsigned short* __restrict__ O) {
    __shared__ unsigned short Ks[2 * 128 * 64]; // dbuf [key][dh], 128B rows, swizzled
    __shared__ unsigned short Vs[2 * 64 * 128]; // dbuf [dh][key], 256B rows, swizzled
    const int tid = threadIdx.x, wid = tid >> 6, lane = tid & 63;
    const int ln31 = lane & 31, hi = lane >> 5;

    // ---- balance remap (512 blocks; dispatch order l = by*8+bx) ----
    const int l = blockIdx.y * 8 + blockIdx.x;
    const int u = l & 255, v = l >> 8;          // v in {0,1}
    const int bh = v * 32 + (u >> 3);           // [0,64)
    const int qt = v ? (7 - (u & 7)) : (u & 7); // [0,8), 256 q rows per qt

    const size_t hoff = (size_t)bh * 2048 * 64;
    const int qrow0 = qt * 256 + wid * 32;   // this wave's first q row
    const int tq = qrow0 + ln31;             // this lane's q row
    const float NEG_INF = -__builtin_inff();

    // Q B-fragments: lane(q=ln31, hi): k = st*16 + hi*8 + e
    short8 qf[4];
    #pragma unroll
    for (int st = 0; st < 4; ++st)
        qf[st] = *(const short8*)(Q + hoff + (size_t)tq * 64 + st * 16 + hi * 8);

    f32x16 oacc[2];
    oacc[0] = (f32x16)(0.f); oacc[1] = (f32x16)(0.f);
    float mrow = NEG_INF, lrow = 0.f;

    const unsigned short* Kh = Kb + hoff;
    const unsigned short* Vh = Vt + hoff;

    auto stage = [&](int buf, int kvb) {
        // 128-key tile: K = 1024 chunks (8/row), V = 1024 chunks (16/row);
        // 512 threads x 2 chunks each per matrix.
        #pragma unroll
        for (int it = 0; it < 2; ++it) {
            int c = it * 512 + tid;            // [0,1024)
            int krow = c >> 3, kcc = c & 7;
            int kccs = kcc ^ (krow & 7);
            gload16(Kh + (size_t)(kvb + krow) * 64 + kccs * 8,
                    (char*)Ks + buf * 16384 + c * 16);
            int vrow = c >> 4, vcc = c & 15;
            int vccs = vcc ^ (vrow & 15);
            gload16(Vh + (size_t)vrow * 2048 + kvb + vccs * 8,
                    (char*)Vs + buf * 16384 + c * 16);
        }
    };

    const int nkv = 2 * qt + 2; // 128-key tiles
    stage(0, 0);
    for (int kv = 0; kv < nkv; ++kv) {
        const int kvb = kv * 128;
        const int cur = kv & 1;
        __syncthreads(); // drains stage(cur)'s vmcnt; fences prior reads of buf cur
        if (kv + 1 < nkv) stage(cur ^ 1, kvb + 128);

        const char* Kbase = (const char*)Ks + cur * 16384;
        const char* Vbase = (const char*)Vs + cur * 16384;

        #pragma unroll
        for (int sub = 0; sub < 2; ++sub) {
            const int kvs = kvb + sub * 64;
            if (kvs > qrow0) continue; // wave-uniform: no unmasked key in subtile

            // ---- S^T = K Q^T : [64 keys x 32 q], two 32-key subtiles ----
            f32x16 s0 = (f32x16)(0.f), s1 = (f32x16)(0.f);
            __builtin_amdgcn_s_setprio(1);
            #pragma unroll
            for (int st = 0; st < 4; ++st) {
                int row0 = sub * 64 + ln31, row1 = sub * 64 + 32 + ln31;
                short8 kf0 = *(const short8*)(Kbase + row0 * 128 +
                                              (((2 * st + hi) ^ (row0 & 7)) << 4));
                short8 kf1 = *(const short8*)(Kbase + row1 * 128 +
                                              (((2 * st + hi) ^ (row1 & 7)) << 4));
                s0 = __builtin_amdgcn_mfma_f32_32x32x16_bf16(kf0, qf[st], s0, 0, 0, 0);
                s1 = __builtin_amdgcn_mfma_f32_32x32x16_bf16(kf1, qf[st], s1, 0, 0, 0);
            }
            __builtin_amdgcn_s_setprio(0);

            // ---- V fragments from LDS, issued BEFORE softmax (latency hides
            // under the exp/max chain). V rows are 256B, 16 chunks/row ----
            short8 vf[4][2];
            #pragma unroll
            for (int m = 0; m < 4; ++m)
                #pragma unroll
                for (int d = 0; d < 2; ++d) {
                    int row = d * 32 + ln31; // dh
                    int slot = (sub * 8 + 2 * m + hi) ^ (row & 15);
                    vf[m][d] = *(const short8*)(Vbase + row * 256 + (slot << 4));
                }

            // ---- causal mask (S pre-scaled via Q, exp2 domain) ----
            if (kvs + 63 > qrow0) {
                const int lim = tq - kvs;
                #pragma unroll
                for (int j = 0; j < 16; ++j) {
                    int krel = (j & 3) + 8 * (j >> 2) + 4 * hi;
                    if (krel > lim)      s0[j] = NEG_INF;
                    if (krel + 32 > lim) s1[j] = NEG_INF;
                }
            }
            // ---- online softmax (exp2 domain; 4-way interleaved chains) ----
            float ma = fmaxf(s0[0], s0[1]), mb = fmaxf(s0[2], s0[3]);
            float mc = fmaxf(s1[0], s1[1]), md = fmaxf(s1[2], s1[3]);
            #pragma unroll
            for (int j = 4; j < 16; j += 4) {
                ma = fmaxf(ma, fmaxf(s0[j], s0[j+1]));
                mb = fmaxf(mb, fmaxf(s0[j+2], s0[j+3]));
                mc = fmaxf(mc, fmaxf(s1[j], s1[j+1]));
                md = fmaxf(md, fmaxf(s1[j+2], s1[j+3]));
            }
            float mloc = fmaxf(fmaxf(ma, mb), fmaxf(mc, md));
            mloc = fmaxf(mloc, __shfl_xor(mloc, 32));
            float mnew = fmaxf(mrow, mloc);
            // bit-exact skip: when all lanes have mloc<=mrow, alpha==1.0 exactly
            if (!__all(mloc <= mrow)) {
                float alpha = exp2f(mrow - mnew);
                lrow *= alpha;
                #pragma unroll
                for (int j = 0; j < 16; ++j) { oacc[0][j] *= alpha; oacc[1][j] *= alpha; }
            }
            mrow = mnew;
            float la = 0.f, lb = 0.f, lc = 0.f, ld = 0.f;
            #pragma unroll
            for (int j = 0; j < 16; j += 2) {
                float p00 = exp2f(s0[j] - mnew), p01 = exp2f(s0[j+1] - mnew);
                float p10 = exp2f(s1[j] - mnew), p11 = exp2f(s1[j+1] - mnew);
                s0[j] = p00; s0[j+1] = p01; s1[j] = p10; s1[j+1] = p11;
                la += p00; lb += p01; lc += p10; ld += p11;
            }
            float ls = (la + lb) + (lc + ld);
            ls += __shfl_xor(ls, 32);
            lrow += ls;

            // ---- O^T += V^T P^T : per k-step m (16 keys), per dh-tile d ----
            __builtin_amdgcn_s_setprio(1);
            #pragma unroll
            for (int m = 0; m < 4; ++m) {
                const int h = m & 1;
                float pa0, pa1, pb0, pb1, pc0, pc1, pd0, pd1;
                if (m < 2) {
                    pa0 = s0[8*h+0]; pa1 = s0[8*h+1]; pc0 = s0[8*h+2]; pc1 = s0[8*h+3];
                    pb0 = s0[8*h+4]; pb1 = s0[8*h+5]; pd0 = s0[8*h+6]; pd1 = s0[8*h+7];
                } else {
                    pa0 = s1[8*h+0]; pa1 = s1[8*h+1]; pc0 = s1[8*h+2]; pc1 = s1[8*h+3];
                    pb0 = s1[8*h+4]; pb1 = s1[8*h+5]; pd0 = s1[8*h+6]; pd1 = s1[8*h+7];
                }
                unsigned int pkA = pack2bf(pa0, pa1), pkC = pack2bf(pc0, pc1);
                unsigned int pkB = pack2bf(pb0, pb1), pkD = pack2bf(pd0, pd1);
                // permlane32_swap: r.x[i]=(i<32)?a[i]:b[i-32], r.y[i]=(i<32)?a[i+32]:b[i]
                u32x2 rAB = __builtin_amdgcn_permlane32_swap(pkA, pkB, false, false);
                u32x2 rCD = __builtin_amdgcn_permlane32_swap(pkC, pkD, false, false);
                u32x4 w;
                w.x = rAB.x;  // e0,e1
                w.y = rCD.x;  // e2,e3
                w.z = rAB.y;  // e4,e5
                w.w = rCD.y;  // e6,e7
                short8 pfrag = __builtin_bit_cast(short8, w);
                #pragma unroll
                for (int d = 0; d < 2; ++d)
                    oacc[d] = __builtin_amdgcn_mfma_f32_32x32x16_bf16(vf[m][d], pfrag, oacc[d], 0, 0, 0);
            }
            __builtin_amdgcn_s_setprio(0);
        }
    }

    // ---- epilogue: lane writes row t = tq, dh varies ----
    const int b = bh >> 4, h = bh & 15;
    const float rinv = 1.0f / lrow;
    unsigned short* orow = O + (size_t)(b * 2048 + tq) * 1024 + h * 64;
    #pragma unroll
    for (int d = 0; d < 2; ++d)
        #pragma unroll
        for (int u2 = 0; u2 < 4; ++u2) {
            int dh0 = d * 32 + u2 * 8 + 4 * hi;
            uint2 w;
            w.x = pack2bf(oacc[d][4*u2+0] * rinv, oacc[d][4*u2+1] * rinv);
            w.y = pack2bf(oacc[d][4*u2+2] * rinv, oacc[d][4*u2+3] * rinv);
            *(uint2*)(orow + dh0) = w;
        }
}

extern "C" void kernel_launch(void* const* d_in, const int* in_sizes, int n_in,
                              void* d_out, int out_size, void* d_ws, size_t ws_size,
                              hipStream_t stream) {
    const float* x     = (const float*)d_in[0];
    const float* Wqkv  = (const float*)d_in[2];
    const float* bqkv  = (const float*)d_in[3];
    const float* Wproj = (const float*)d_in[4];
    const float* bproj = (const float*)d_in[5];
    float* out = (float*)d_out;

    // ws layout (72 MB): Ob aliases xb — xb is dead after gemm<0> (launch 4),
    // Ob is first written by attn (launch 5). Stream order makes this safe.
    char* ws = (char*)d_ws;
    unsigned short* xb  = (unsigned short*)(ws);                    // 16MB [0,16)
    unsigned short* Ob  = (unsigned short*)(ws);                    // alias of xb
    unsigned short* WqT = (unsigned short*)(ws + (16u << 20));      // 6MB  [3072][1024]
    unsigned short* WpT = (unsigned short*)(ws + (22u << 20));      // 2MB  [1024][1024]
    unsigned short* Qb  = (unsigned short*)(ws + (24u << 20));      // 16MB [64][2048][64]
    unsigned short* Kb  = (unsigned short*)(ws + (40u << 20));      // 16MB
    unsigned short* Vt  = (unsigned short*)(ws + (56u << 20));      // 16MB [64][64][2048]

    cvt_bf16_kernel<<<2048, 256, 0, stream>>>(x, xb, (8192 * 1024) / 4);
    transpose_cvt_kernel<<<dim3(96, 32), 256, 0, stream>>>(Wqkv, WqT, 1024, 3072);
    transpose_cvt_kernel<<<dim3(32, 32), 256, 0, stream>>>(Wproj, WpT, 1024, 1024);
    gemm_bt<0><<<dim3(64, 24), 256, 0, stream>>>(xb, WqT, bqkv, Qb, Kb, Vt, nullptr,
                                                 8192, 3072, 1024);
    attn_kernel<<<dim3(8, 64), 512, 0, stream>>>(Qb, Kb, Vt, Ob);
    gemm_bt<1><<<dim3(64, 8), 256, 0, stream>>>(Ob, WpT, bproj, nullptr, nullptr,
                                                nullptr, out, 8192, 1024, 1024);
}

// Round 22
// 204.484 us; speedup vs baseline: 1.0646x; 1.0116x over previous
//
#include <hip/hip_runtime.h>
#include <hip/hip_bf16.h>

typedef __attribute__((ext_vector_type(8))) short short8;
typedef __attribute__((ext_vector_type(4))) float f32x4;
typedef __attribute__((ext_vector_type(16))) float f32x16;
typedef __attribute__((ext_vector_type(4))) unsigned int u32x4;
typedef __attribute__((ext_vector_type(2))) unsigned int u32x2;

#define DEV static __device__ __forceinline__

// hardware bf16 convert (RNE, lowers to v_cvt_pk_bf16_f32)
DEV unsigned short bfc(float f) {
    __bf16 h = (__bf16)f;
    return __builtin_bit_cast(unsigned short, h);
}

DEV unsigned int pack2bf(float lo, float hi) {
    return (unsigned int)bfc(lo) | ((unsigned int)bfc(hi) << 16);
}

DEV void gload16(const void* g, void* l) {
    __builtin_amdgcn_global_load_lds(
        (const __attribute__((address_space(1))) unsigned int*)g,
        (__attribute__((address_space(3))) unsigned int*)l, 16, 0, 0);
}

// ---------------- elementwise f32 -> bf16 ----------------
__global__ void cvt_bf16_kernel(const float* __restrict__ in,
                                unsigned short* __restrict__ out, int n4) {
    int stride = gridDim.x * blockDim.x;
    for (int i = blockIdx.x * blockDim.x + threadIdx.x; i < n4; i += stride) {
        float4 v = reinterpret_cast<const float4*>(in)[i];
        ushort4 o;
        o.x = bfc(v.x); o.y = bfc(v.y); o.z = bfc(v.z); o.w = bfc(v.w);
        reinterpret_cast<ushort4*>(out)[i] = o;
    }
}

// ---------------- W [K][N] f32 -> W^T [N][K] bf16 ----------------
__global__ void transpose_cvt_kernel(const float* __restrict__ in,
                                     unsigned short* __restrict__ out,
                                     int K, int N) {
    __shared__ float tile[32][33];
    int n0 = blockIdx.x * 32, k0 = blockIdx.y * 32;
    int tx = threadIdx.x & 31, ty = threadIdx.x >> 5; // 32 x 8
    #pragma unroll
    for (int i = 0; i < 32; i += 8)
        tile[ty + i][tx] = in[(size_t)(k0 + ty + i) * N + n0 + tx];
    __syncthreads();
    #pragma unroll
    for (int i = 0; i < 32; i += 8)
        out[(size_t)(n0 + ty + i) * K + k0 + tx] = bfc(tile[tx][ty + i]);
}

// ---------------- bf16 GEMM: C[M,N] = A[M,K] * Bt[N,K]^T + bias ----------------
// EPI 0: scatter to Q (pre-scaled by log2e/sqrt(64)), K [BH,T,64], Vt [BH,64,T].
// EPI 1: fp32 out [M,N].
// R22: depth-2 counted-vmcnt pipeline (T4): 4 LDS buffers; per iter
//   stage(kt+2) -> s_waitcnt vmcnt(8) -> s_barrier -> compute(kt).
// vmcnt(8) leaves tiles kt+1,kt+2 in flight => tile kt landed (4 loads/thread/
// tile). Never drains to 0 in steady state. Race audit in session notes:
// R->W safe (reads of buf[(kt+2)&3] consumed 2 barriers earlier), W->R safe
// (vmcnt+barrier). All branches wave-uniform.
template <int EPI>
__global__ __launch_bounds__(256) void gemm_bt(
    const unsigned short* __restrict__ A,
    const unsigned short* __restrict__ Bt,
    const float* __restrict__ bias,
    unsigned short* __restrict__ oQ,
    unsigned short* __restrict__ oK,
    unsigned short* __restrict__ oVt,
    float* __restrict__ oP,
    int M, int N, int K) {
    __shared__ unsigned short As[4 * 128 * 32]; // 4 bufs x 8KB
    __shared__ unsigned short Bs[4 * 128 * 32];
    const int tid = threadIdx.x;
    const int wid = tid >> 6, lane = tid & 63;
    const int r = lane & 15, g = lane >> 4;
    const int wm = wid >> 1, wn = wid & 1;
    const int bm = blockIdx.x, bn = blockIdx.y;

    f32x4 acc[4][4];
    #pragma unroll
    for (int i = 0; i < 4; i++)
        #pragma unroll
        for (int j = 0; j < 4; j++) acc[i][j] = (f32x4)(0.f);

    auto stage = [&](int buf, int k0) {
        #pragma unroll
        for (int it = 0; it < 2; ++it) {
            int c = it * 256 + wid * 64 + lane; // 16B chunk id, 4 chunks/row
            int row = c >> 2, cc = c & 3;
            int ccs = cc ^ ((row >> 1) & 3);    // swizzled source chunk
            gload16(A + (size_t)(bm * 128 + row) * K + k0 + ccs * 8,
                    (char*)As + buf * 8192 + (it * 256 + wid * 64) * 16);
            gload16(Bt + (size_t)(bn * 128 + row) * K + k0 + ccs * 8,
                    (char*)Bs + buf * 8192 + (it * 256 + wid * 64) * 16);
        }
    };

    const int nk = K >> 5; // 32 for K=1024
    stage(0, 0);
    stage(1, 32);
    for (int kt = 0; kt < nk; ++kt) {
        if (kt + 2 < nk) {
            stage((kt + 2) & 3, (kt + 2) << 5);
            asm volatile("s_waitcnt vmcnt(8)" ::: "memory");
        } else if (kt + 1 < nk) {
            asm volatile("s_waitcnt vmcnt(4)" ::: "memory");
        } else {
            asm volatile("s_waitcnt vmcnt(0)" ::: "memory");
        }
        __builtin_amdgcn_sched_barrier(0);
        __builtin_amdgcn_s_barrier();
        __builtin_amdgcn_sched_barrier(0);

        const char* Abase = (const char*)As + (kt & 3) * 8192;
        const char* Bbase = (const char*)Bs + (kt & 3) * 8192;
        short8 af[4], bfr[4];
        #pragma unroll
        for (int mi = 0; mi < 4; ++mi) {
            int row = wm * 64 + mi * 16 + r;
            af[mi] = *(const short8*)(Abase + row * 64 +
                                      ((g ^ ((row >> 1) & 3)) << 4));
        }
        #pragma unroll
        for (int ni = 0; ni < 4; ++ni) {
            int row = wn * 64 + ni * 16 + r;
            bfr[ni] = *(const short8*)(Bbase + row * 64 +
                                       ((g ^ ((row >> 1) & 3)) << 4));
        }
        __builtin_amdgcn_s_setprio(1);
        #pragma unroll
        for (int mi = 0; mi < 4; ++mi)
            #pragma unroll
            for (int ni = 0; ni < 4; ++ni)
                acc[mi][ni] = __builtin_amdgcn_mfma_f32_16x16x32_bf16(
                    af[mi], bfr[ni], acc[mi][ni], 0, 0, 0);
        __builtin_amdgcn_s_setprio(0);
    }

    const float QSCALE = 0.18033688011112042f; // log2(e)/sqrt(64); exp2 domain
    #pragma unroll
    for (int ni = 0; ni < 4; ++ni) {
        int n = bn * 128 + wn * 64 + ni * 16 + r;
        float bb = bias[n];
        #pragma unroll
        for (int mi = 0; mi < 4; ++mi) {
            #pragma unroll
            for (int rr = 0; rr < 4; ++rr) {
                int m = bm * 128 + wm * 64 + mi * 16 + g * 4 + rr;
                float v = acc[mi][ni][rr] + bb;
                if (EPI == 0) {
                    int b = m >> 11, t = m & 2047;
                    int s = n >> 10, hh = (n >> 6) & 15, dh = n & 63;
                    size_t bh = (size_t)(b * 16 + hh);
                    if (s == 0)      oQ[(bh * 2048 + t) * 64 + dh] = bfc(v * QSCALE);
                    else if (s == 1) oK[(bh * 2048 + t) * 64 + dh] = bfc(v);
                    else             oVt[(bh * 64 + dh) * 2048 + t] = bfc(v);
                } else {
                    oP[(size_t)m * N + n] = v;
                }
            }
        }
    }
}

// ---------------- causal flash attention, swapped-QK 32x32 MFMA ----------------
// Q (pre-scaled, exp2 domain): [BH][2048][64] bf16 ; Kb same ; Vt: [BH][64][2048]
// O: [B][2048][1024] bf16. 8 waves x 32 q-rows = 256 rows/block (512 thr).
// KVBLK=128 staged per barrier, two sequential 64-key passes; permlane32_swap
// P-exchange (R20-verified: 96.6us, bit-exact). Unchanged from R20 best.
__global__ __launch_bounds__(512, 2) void attn_kernel(
    const unsigned short* __restrict__ Q,
    const unsigned short* __restrict__ Kb,
    const unsigned short* __restrict__ Vt,
    unsigned short* __restrict__ O) {
    __shared__ unsigned short Ks[2 * 128 * 64]; // dbuf [key][dh], 128B rows, swizzled
    __shared__ unsigned short Vs[2 * 64 * 128]; // dbuf [dh][key], 256B rows, swizzled
    const int tid = threadIdx.x, wid = tid >> 6, lane = tid & 63;
    const int ln31 = lane & 31, hi = lane >> 5;

    // ---- balance remap (512 blocks; dispatch order l = by*8+bx) ----
    const int l = blockIdx.y * 8 + blockIdx.x;
    const int u = l & 255, v = l >> 8;          // v in {0,1}
    const int bh = v * 32 + (u >> 3);           // [0,64)
    const int qt = v ? (7 - (u & 7)) : (u & 7); // [0,8), 256 q rows per qt

    const size_t hoff = (size_t)bh * 2048 * 64;
    const int qrow0 = qt * 256 + wid * 32;   // this wave's first q row
    const int tq = qrow0 + ln31;             // this lane's q row
    const float NEG_INF = -__builtin_inff();

    // Q B-fragments: lane(q=ln31, hi): k = st*16 + hi*8 + e
    short8 qf[4];
    #pragma unroll
    for (int st = 0; st < 4; ++st)
        qf[st] = *(const short8*)(Q + hoff + (size_t)tq * 64 + st * 16 + hi * 8);

    f32x16 oacc[2];
    oacc[0] = (f32x16)(0.f); oacc[1] = (f32x16)(0.f);
    float mrow = NEG_INF, lrow = 0.f;

    const unsigned short* Kh = Kb + hoff;
    const unsigned short* Vh = Vt + hoff;

    auto stage = [&](int buf, int kvb) {
        // 128-key tile: K = 1024 chunks (8/row), V = 1024 chunks (16/row);
        // 512 threads x 2 chunks each per matrix.
        #pragma unroll
        for (int it = 0; it < 2; ++it) {
            int c = it * 512 + tid;            // [0,1024)
            int krow = c >> 3, kcc = c & 7;
            int kccs = kcc ^ (krow & 7);
            gload16(Kh + (size_t)(kvb + krow) * 64 + kccs * 8,
                    (char*)Ks + buf * 16384 + c * 16);
            int vrow = c >> 4, vcc = c & 15;
            int vccs = vcc ^ (vrow & 15);
            gload16(Vh + (size_t)vrow * 2048 + kvb + vccs * 8,
                    (char*)Vs + buf * 16384 + c * 16);
        }
    };

    const int nkv = 2 * qt + 2; // 128-key tiles
    stage(0, 0);
    for (int kv = 0; kv < nkv; ++kv) {
        const int kvb = kv * 128;
        const int cur = kv & 1;
        __syncthreads(); // drains stage(cur)'s vmcnt; fences prior reads of buf cur
        if (kv + 1 < nkv) stage(cur ^ 1, kvb + 128);

        const char* Kbase = (const char*)Ks + cur * 16384;
        const char* Vbase = (const char*)Vs + cur * 16384;

        #pragma unroll
        for (int sub = 0; sub < 2; ++sub) {
            const int kvs = kvb + sub * 64;
            if (kvs > qrow0) continue; // wave-uniform: no unmasked key in subtile

            // ---- S^T = K Q^T : [64 keys x 32 q], two 32-key subtiles ----
            f32x16 s0 = (f32x16)(0.f), s1 = (f32x16)(0.f);
            __builtin_amdgcn_s_setprio(1);
            #pragma unroll
            for (int st = 0; st < 4; ++st) {
                int row0 = sub * 64 + ln31, row1 = sub * 64 + 32 + ln31;
                short8 kf0 = *(const short8*)(Kbase + row0 * 128 +
                                              (((2 * st + hi) ^ (row0 & 7)) << 4));
                short8 kf1 = *(const short8*)(Kbase + row1 * 128 +
                                              (((2 * st + hi) ^ (row1 & 7)) << 4));
                s0 = __builtin_amdgcn_mfma_f32_32x32x16_bf16(kf0, qf[st], s0, 0, 0, 0);
                s1 = __builtin_amdgcn_mfma_f32_32x32x16_bf16(kf1, qf[st], s1, 0, 0, 0);
            }
            __builtin_amdgcn_s_setprio(0);

            // ---- V fragments from LDS, issued BEFORE softmax (latency hides
            // under the exp/max chain). V rows are 256B, 16 chunks/row ----
            short8 vf[4][2];
            #pragma unroll
            for (int m = 0; m < 4; ++m)
                #pragma unroll
                for (int d = 0; d < 2; ++d) {
                    int row = d * 32 + ln31; // dh
                    int slot = (sub * 8 + 2 * m + hi) ^ (row & 15);
                    vf[m][d] = *(const short8*)(Vbase + row * 256 + (slot << 4));
                }

            // ---- causal mask (S pre-scaled via Q, exp2 domain) ----
            if (kvs + 63 > qrow0) {
                const int lim = tq - kvs;
                #pragma unroll
                for (int j = 0; j < 16; ++j) {
                    int krel = (j & 3) + 8 * (j >> 2) + 4 * hi;
                    if (krel > lim)      s0[j] = NEG_INF;
                    if (krel + 32 > lim) s1[j] = NEG_INF;
                }
            }
            // ---- online softmax (exp2 domain; 4-way interleaved chains) ----
            float ma = fmaxf(s0[0], s0[1]), mb = fmaxf(s0[2], s0[3]);
            float mc = fmaxf(s1[0], s1[1]), md = fmaxf(s1[2], s1[3]);
            #pragma unroll
            for (int j = 4; j < 16; j += 4) {
                ma = fmaxf(ma, fmaxf(s0[j], s0[j+1]));
                mb = fmaxf(mb, fmaxf(s0[j+2], s0[j+3]));
                mc = fmaxf(mc, fmaxf(s1[j], s1[j+1]));
                md = fmaxf(md, fmaxf(s1[j+2], s1[j+3]));
            }
            float mloc = fmaxf(fmaxf(ma, mb), fmaxf(mc, md));
            mloc = fmaxf(mloc, __shfl_xor(mloc, 32));
            float mnew = fmaxf(mrow, mloc);
            // bit-exact skip: when all lanes have mloc<=mrow, alpha==1.0 exactly
            if (!__all(mloc <= mrow)) {
                float alpha = exp2f(mrow - mnew);
                lrow *= alpha;
                #pragma unroll
                for (int j = 0; j < 16; ++j) { oacc[0][j] *= alpha; oacc[1][j] *= alpha; }
            }
            mrow = mnew;
            float la = 0.f, lb = 0.f, lc = 0.f, ld = 0.f;
            #pragma unroll
            for (int j = 0; j < 16; j += 2) {
                float p00 = exp2f(s0[j] - mnew), p01 = exp2f(s0[j+1] - mnew);
                float p10 = exp2f(s1[j] - mnew), p11 = exp2f(s1[j+1] - mnew);
                s0[j] = p00; s0[j+1] = p01; s1[j] = p10; s1[j+1] = p11;
                la += p00; lb += p01; lc += p10; ld += p11;
            }
            float ls = (la + lb) + (lc + ld);
            ls += __shfl_xor(ls, 32);
            lrow += ls;

            // ---- O^T += V^T P^T : per k-step m (16 keys), per dh-tile d ----
            __builtin_amdgcn_s_setprio(1);
            #pragma unroll
            for (int m = 0; m < 4; ++m) {
                const int h = m & 1;
                float pa0, pa1, pb0, pb1, pc0, pc1, pd0, pd1;
                if (m < 2) {
                    pa0 = s0[8*h+0]; pa1 = s0[8*h+1]; pc0 = s0[8*h+2]; pc1 = s0[8*h+3];
                    pb0 = s0[8*h+4]; pb1 = s0[8*h+5]; pd0 = s0[8*h+6]; pd1 = s0[8*h+7];
                } else {
                    pa0 = s1[8*h+0]; pa1 = s1[8*h+1]; pc0 = s1[8*h+2]; pc1 = s1[8*h+3];
                    pb0 = s1[8*h+4]; pb1 = s1[8*h+5]; pd0 = s1[8*h+6]; pd1 = s1[8*h+7];
                }
                unsigned int pkA = pack2bf(pa0, pa1), pkC = pack2bf(pc0, pc1);
                unsigned int pkB = pack2bf(pb0, pb1), pkD = pack2bf(pd0, pd1);
                // permlane32_swap: r.x[i]=(i<32)?a[i]:b[i-32], r.y[i]=(i<32)?a[i+32]:b[i]
                u32x2 rAB = __builtin_amdgcn_permlane32_swap(pkA, pkB, false, false);
                u32x2 rCD = __builtin_amdgcn_permlane32_swap(pkC, pkD, false, false);
                u32x4 w;
                w.x = rAB.x;  // e0,e1
                w.y = rCD.x;  // e2,e3
                w.z = rAB.y;  // e4,e5
                w.w = rCD.y;  // e6,e7
                short8 pfrag = __builtin_bit_cast(short8, w);
                #pragma unroll
                for (int d = 0; d < 2; ++d)
                    oacc[d] = __builtin_amdgcn_mfma_f32_32x32x16_bf16(vf[m][d], pfrag, oacc[d], 0, 0, 0);
            }
            __builtin_amdgcn_s_setprio(0);
        }
    }

    // ---- epilogue: lane writes row t = tq, dh varies ----
    const int b = bh >> 4, h = bh & 15;
    const float rinv = 1.0f / lrow;
    unsigned short* orow = O + (size_t)(b * 2048 + tq) * 1024 + h * 64;
    #pragma unroll
    for (int d = 0; d < 2; ++d)
        #pragma unroll
        for (int u2 = 0; u2 < 4; ++u2) {
            int dh0 = d * 32 + u2 * 8 + 4 * hi;
            uint2 w;
            w.x = pack2bf(oacc[d][4*u2+0] * rinv, oacc[d][4*u2+1] * rinv);
            w.y = pack2bf(oacc[d][4*u2+2] * rinv, oacc[d][4*u2+3] * rinv);
            *(uint2*)(orow + dh0) = w;
        }
}

extern "C" void kernel_launch(void* const* d_in, const int* in_sizes, int n_in,
                              void* d_out, int out_size, void* d_ws, size_t ws_size,
                              hipStream_t stream) {
    const float* x     = (const float*)d_in[0];
    const float* Wqkv  = (const float*)d_in[2];
    const float* bqkv  = (const float*)d_in[3];
    const float* Wproj = (const float*)d_in[4];
    const float* bproj = (const float*)d_in[5];
    float* out = (float*)d_out;

    // ws layout (72 MB): Ob aliases xb — xb is dead after gemm<0> (launch 4),
    // Ob is first written by attn (launch 5). Stream order makes this safe.
    char* ws = (char*)d_ws;
    unsigned short* xb  = (unsigned short*)(ws);                    // 16MB [0,16)
    unsigned short* Ob  = (unsigned short*)(ws);                    // alias of xb
    unsigned short* WqT = (unsigned short*)(ws + (16u << 20));      // 6MB  [3072][1024]
    unsigned short* WpT = (unsigned short*)(ws + (22u << 20));      // 2MB  [1024][1024]
    unsigned short* Qb  = (unsigned short*)(ws + (24u << 20));      // 16MB [64][2048][64]
    unsigned short* Kb  = (unsigned short*)(ws + (40u << 20));      // 16MB
    unsigned short* Vt  = (unsigned short*)(ws + (56u << 20));      // 16MB [64][64][2048]

    cvt_bf16_kernel<<<2048, 256, 0, stream>>>(x, xb, (8192 * 1024) / 4);
    transpose_cvt_kernel<<<dim3(96, 32), 256, 0, stream>>>(Wqkv, WqT, 1024, 3072);
    transpose_cvt_kernel<<<dim3(32, 32), 256, 0, stream>>>(Wproj, WpT, 1024, 1024);
    gemm_bt<0><<<dim3(64, 24), 256, 0, stream>>>(xb, WqT, bqkv, Qb, Kb, Vt, nullptr,
                                                 8192, 3072, 1024);
    attn_kernel<<<dim3(8, 64), 512, 0, stream>>>(Qb, Kb, Vt, Ob);
    gemm_bt<1><<<dim3(64, 8), 256, 0, stream>>>(Ob, WpT, bproj, nullptr, nullptr,
                                                nullptr, out, 8192, 1024, 1024);
}

// Round 23
// 200.866 us; speedup vs baseline: 1.0837x; 1.0180x over previous
//
#include <hip/hip_runtime.h>
#include <hip/hip_bf16.h>

typedef __attribute__((ext_vector_type(8))) short short8;
typedef __attribute__((ext_vector_type(4))) float f32x4;
typedef __attribute__((ext_vector_type(16))) float f32x16;
typedef __attribute__((ext_vector_type(4))) unsigned int u32x4;
typedef __attribute__((ext_vector_type(2))) unsigned int u32x2;

#define DEV static __device__ __forceinline__

// hardware bf16 convert (RNE, lowers to v_cvt_pk_bf16_f32)
DEV unsigned short bfc(float f) {
    __bf16 h = (__bf16)f;
    return __builtin_bit_cast(unsigned short, h);
}

DEV unsigned int pack2bf(float lo, float hi) {
    return (unsigned int)bfc(lo) | ((unsigned int)bfc(hi) << 16);
}

DEV void gload16(const void* g, void* l) {
    __builtin_amdgcn_global_load_lds(
        (const __attribute__((address_space(1))) unsigned int*)g,
        (__attribute__((address_space(3))) unsigned int*)l, 16, 0, 0);
}

// ---------------- elementwise f32 -> bf16 ----------------
__global__ void cvt_bf16_kernel(const float* __restrict__ in,
                                unsigned short* __restrict__ out, int n4) {
    int stride = gridDim.x * blockDim.x;
    for (int i = blockIdx.x * blockDim.x + threadIdx.x; i < n4; i += stride) {
        float4 v = reinterpret_cast<const float4*>(in)[i];
        ushort4 o;
        o.x = bfc(v.x); o.y = bfc(v.y); o.z = bfc(v.z); o.w = bfc(v.w);
        reinterpret_cast<ushort4*>(out)[i] = o;
    }
}

// ---------------- W [K][N] f32 -> W^T [N][K] bf16 ----------------
__global__ void transpose_cvt_kernel(const float* __restrict__ in,
                                     unsigned short* __restrict__ out,
                                     int K, int N) {
    __shared__ float tile[32][33];
    int n0 = blockIdx.x * 32, k0 = blockIdx.y * 32;
    int tx = threadIdx.x & 31, ty = threadIdx.x >> 5; // 32 x 8
    #pragma unroll
    for (int i = 0; i < 32; i += 8)
        tile[ty + i][tx] = in[(size_t)(k0 + ty + i) * N + n0 + tx];
    __syncthreads();
    #pragma unroll
    for (int i = 0; i < 32; i += 8)
        out[(size_t)(n0 + ty + i) * K + k0 + tx] = bfc(tile[tx][ty + i]);
}

// ---------------- bf16 GEMM: C[M,N] = A[M,K] * Bt[N,K]^T + bias ----------------
// EPI 0: scatter to Q (pre-scaled by log2e/sqrt(64)), K [BH,T,64], Vt [BH,64,T].
// EPI 1: fp32 out [M,N].
// R23: BK=64 double-buffered 2-phase. Halves barrier count vs BK=32 (16 steps
// for K=1024); 32 MFMA per step cover the depth-1 prefetch latency. LDS 64KB
// (2 bufs x 16KB x {A,B}), same residency as R22's 4-buf ring. Rows are 128B /
// 8 chunks; XOR swizzle cc^(row&7) (attn-K proven). K order unchanged ->
// bit-identical accumulation.
template <int EPI>
__global__ __launch_bounds__(256) void gemm_bt(
    const unsigned short* __restrict__ A,
    const unsigned short* __restrict__ Bt,
    const float* __restrict__ bias,
    unsigned short* __restrict__ oQ,
    unsigned short* __restrict__ oK,
    unsigned short* __restrict__ oVt,
    float* __restrict__ oP,
    int M, int N, int K) {
    __shared__ unsigned short As[2 * 128 * 64]; // dbuf, 16KB per buffer
    __shared__ unsigned short Bs[2 * 128 * 64];
    const int tid = threadIdx.x;
    const int wid = tid >> 6, lane = tid & 63;
    const int r = lane & 15, g = lane >> 4;
    const int wm = wid >> 1, wn = wid & 1;
    const int bm = blockIdx.x, bn = blockIdx.y;

    f32x4 acc[4][4];
    #pragma unroll
    for (int i = 0; i < 4; i++)
        #pragma unroll
        for (int j = 0; j < 4; j++) acc[i][j] = (f32x4)(0.f);

    auto stage = [&](int buf, int k0) {
        // 128x64 tile per matrix = 1024 chunks of 16B; 256 thr x 4 chunks.
        #pragma unroll
        for (int it = 0; it < 4; ++it) {
            int c = it * 256 + tid;          // [0,1024)
            int row = c >> 3, cc = c & 7;    // 8 chunks per 128B row
            int ccs = cc ^ (row & 7);        // swizzled source chunk
            gload16(A + (size_t)(bm * 128 + row) * K + k0 + ccs * 8,
                    (char*)As + buf * 16384 + c * 16);
            gload16(Bt + (size_t)(bn * 128 + row) * K + k0 + ccs * 8,
                    (char*)Bs + buf * 16384 + c * 16);
        }
    };

    const int nk = K >> 6; // 16 for K=1024
    stage(0, 0);
    for (int kt = 0; kt < nk; ++kt) {
        const int cur = kt & 1;
        __syncthreads(); // drains stage(cur)'s vmcnt; fences prior reads of buf cur
        if (kt + 1 < nk) stage(cur ^ 1, (kt + 1) << 6);

        const char* Abase = (const char*)As + cur * 16384;
        const char* Bbase = (const char*)Bs + cur * 16384;
        #pragma unroll
        for (int kk = 0; kk < 2; ++kk) {
            short8 af[4], bfr[4];
            #pragma unroll
            for (int mi = 0; mi < 4; ++mi) {
                int row = wm * 64 + mi * 16 + r;
                af[mi] = *(const short8*)(Abase + row * 128 +
                                          (((kk * 4 + g) ^ (row & 7)) << 4));
            }
            #pragma unroll
            for (int ni = 0; ni < 4; ++ni) {
                int row = wn * 64 + ni * 16 + r;
                bfr[ni] = *(const short8*)(Bbase + row * 128 +
                                           (((kk * 4 + g) ^ (row & 7)) << 4));
            }
            __builtin_amdgcn_s_setprio(1);
            #pragma unroll
            for (int mi = 0; mi < 4; ++mi)
                #pragma unroll
                for (int ni = 0; ni < 4; ++ni)
                    acc[mi][ni] = __builtin_amdgcn_mfma_f32_16x16x32_bf16(
                        af[mi], bfr[ni], acc[mi][ni], 0, 0, 0);
            __builtin_amdgcn_s_setprio(0);
        }
    }

    const float QSCALE = 0.18033688011112042f; // log2(e)/sqrt(64); exp2 domain
    #pragma unroll
    for (int ni = 0; ni < 4; ++ni) {
        int n = bn * 128 + wn * 64 + ni * 16 + r;
        float bb = bias[n];
        #pragma unroll
        for (int mi = 0; mi < 4; ++mi) {
            #pragma unroll
            for (int rr = 0; rr < 4; ++rr) {
                int m = bm * 128 + wm * 64 + mi * 16 + g * 4 + rr;
                float v = acc[mi][ni][rr] + bb;
                if (EPI == 0) {
                    int b = m >> 11, t = m & 2047;
                    int s = n >> 10, hh = (n >> 6) & 15, dh = n & 63;
                    size_t bh = (size_t)(b * 16 + hh);
                    if (s == 0)      oQ[(bh * 2048 + t) * 64 + dh] = bfc(v * QSCALE);
                    else if (s == 1) oK[(bh * 2048 + t) * 64 + dh] = bfc(v);
                    else             oVt[(bh * 64 + dh) * 2048 + t] = bfc(v);
                } else {
                    oP[(size_t)m * N + n] = v;
                }
            }
        }
    }
}

// ---------------- causal flash attention, swapped-QK 32x32 MFMA ----------------
// Q (pre-scaled, exp2 domain): [BH][2048][64] bf16 ; Kb same ; Vt: [BH][64][2048]
// O: [B][2048][1024] bf16. 8 waves x 32 q-rows = 256 rows/block (512 thr).
// KVBLK=128 staged per barrier, two sequential 64-key passes; permlane32_swap
// P-exchange (R20-verified: 96.6us, bit-exact). Unchanged from R20 best.
__global__ __launch_bounds__(512, 2) void attn_kernel(
    const unsigned short* __restrict__ Q,
    const unsigned short* __restrict__ Kb,
    const unsigned short* __restrict__ Vt,
    unsigned short* __restrict__ O) {
    __shared__ unsigned short Ks[2 * 128 * 64]; // dbuf [key][dh], 128B rows, swizzled
    __shared__ unsigned short Vs[2 * 64 * 128]; // dbuf [dh][key], 256B rows, swizzled
    const int tid = threadIdx.x, wid = tid >> 6, lane = tid & 63;
    const int ln31 = lane & 31, hi = lane >> 5;

    // ---- balance remap (512 blocks; dispatch order l = by*8+bx) ----
    const int l = blockIdx.y * 8 + blockIdx.x;
    const int u = l & 255, v = l >> 8;          // v in {0,1}
    const int bh = v * 32 + (u >> 3);           // [0,64)
    const int qt = v ? (7 - (u & 7)) : (u & 7); // [0,8), 256 q rows per qt

    const size_t hoff = (size_t)bh * 2048 * 64;
    const int qrow0 = qt * 256 + wid * 32;   // this wave's first q row
    const int tq = qrow0 + ln31;             // this lane's q row
    const float NEG_INF = -__builtin_inff();

    // Q B-fragments: lane(q=ln31, hi): k = st*16 + hi*8 + e
    short8 qf[4];
    #pragma unroll
    for (int st = 0; st < 4; ++st)
        qf[st] = *(const short8*)(Q + hoff + (size_t)tq * 64 + st * 16 + hi * 8);

    f32x16 oacc[2];
    oacc[0] = (f32x16)(0.f); oacc[1] = (f32x16)(0.f);
    float mrow = NEG_INF, lrow = 0.f;

    const unsigned short* Kh = Kb + hoff;
    const unsigned short* Vh = Vt + hoff;

    auto stage = [&](int buf, int kvb) {
        // 128-key tile: K = 1024 chunks (8/row), V = 1024 chunks (16/row);
        // 512 threads x 2 chunks each per matrix.
        #pragma unroll
        for (int it = 0; it < 2; ++it) {
            int c = it * 512 + tid;            // [0,1024)
            int krow = c >> 3, kcc = c & 7;
            int kccs = kcc ^ (krow & 7);
            gload16(Kh + (size_t)(kvb + krow) * 64 + kccs * 8,
                    (char*)Ks + buf * 16384 + c * 16);
            int vrow = c >> 4, vcc = c & 15;
            int vccs = vcc ^ (vrow & 15);
            gload16(Vh + (size_t)vrow * 2048 + kvb + vccs * 8,
                    (char*)Vs + buf * 16384 + c * 16);
        }
    };

    const int nkv = 2 * qt + 2; // 128-key tiles
    stage(0, 0);
    for (int kv = 0; kv < nkv; ++kv) {
        const int kvb = kv * 128;
        const int cur = kv & 1;
        __syncthreads(); // drains stage(cur)'s vmcnt; fences prior reads of buf cur
        if (kv + 1 < nkv) stage(cur ^ 1, kvb + 128);

        const char* Kbase = (const char*)Ks + cur * 16384;
        const char* Vbase = (const char*)Vs + cur * 16384;

        #pragma unroll
        for (int sub = 0; sub < 2; ++sub) {
            const int kvs = kvb + sub * 64;
            if (kvs > qrow0) continue; // wave-uniform: no unmasked key in subtile

            // ---- S^T = K Q^T : [64 keys x 32 q], two 32-key subtiles ----
            f32x16 s0 = (f32x16)(0.f), s1 = (f32x16)(0.f);
            __builtin_amdgcn_s_setprio(1);
            #pragma unroll
            for (int st = 0; st < 4; ++st) {
                int row0 = sub * 64 + ln31, row1 = sub * 64 + 32 + ln31;
                short8 kf0 = *(const short8*)(Kbase + row0 * 128 +
                                              (((2 * st + hi) ^ (row0 & 7)) << 4));
                short8 kf1 = *(const short8*)(Kbase + row1 * 128 +
                                              (((2 * st + hi) ^ (row1 & 7)) << 4));
                s0 = __builtin_amdgcn_mfma_f32_32x32x16_bf16(kf0, qf[st], s0, 0, 0, 0);
                s1 = __builtin_amdgcn_mfma_f32_32x32x16_bf16(kf1, qf[st], s1, 0, 0, 0);
            }
            __builtin_amdgcn_s_setprio(0);

            // ---- V fragments from LDS, issued BEFORE softmax (latency hides
            // under the exp/max chain). V rows are 256B, 16 chunks/row ----
            short8 vf[4][2];
            #pragma unroll
            for (int m = 0; m < 4; ++m)
                #pragma unroll
                for (int d = 0; d < 2; ++d) {
                    int row = d * 32 + ln31; // dh
                    int slot = (sub * 8 + 2 * m + hi) ^ (row & 15);
                    vf[m][d] = *(const short8*)(Vbase + row * 256 + (slot << 4));
                }

            // ---- causal mask (S pre-scaled via Q, exp2 domain) ----
            if (kvs + 63 > qrow0) {
                const int lim = tq - kvs;
                #pragma unroll
                for (int j = 0; j < 16; ++j) {
                    int krel = (j & 3) + 8 * (j >> 2) + 4 * hi;
                    if (krel > lim)      s0[j] = NEG_INF;
                    if (krel + 32 > lim) s1[j] = NEG_INF;
                }
            }
            // ---- online softmax (exp2 domain; 4-way interleaved chains) ----
            float ma = fmaxf(s0[0], s0[1]), mb = fmaxf(s0[2], s0[3]);
            float mc = fmaxf(s1[0], s1[1]), md = fmaxf(s1[2], s1[3]);
            #pragma unroll
            for (int j = 4; j < 16; j += 4) {
                ma = fmaxf(ma, fmaxf(s0[j], s0[j+1]));
                mb = fmaxf(mb, fmaxf(s0[j+2], s0[j+3]));
                mc = fmaxf(mc, fmaxf(s1[j], s1[j+1]));
                md = fmaxf(md, fmaxf(s1[j+2], s1[j+3]));
            }
            float mloc = fmaxf(fmaxf(ma, mb), fmaxf(mc, md));
            mloc = fmaxf(mloc, __shfl_xor(mloc, 32));
            float mnew = fmaxf(mrow, mloc);
            // bit-exact skip: when all lanes have mloc<=mrow, alpha==1.0 exactly
            if (!__all(mloc <= mrow)) {
                float alpha = exp2f(mrow - mnew);
                lrow *= alpha;
                #pragma unroll
                for (int j = 0; j < 16; ++j) { oacc[0][j] *= alpha; oacc[1][j] *= alpha; }
            }
            mrow = mnew;
            float la = 0.f, lb = 0.f, lc = 0.f, ld = 0.f;
            #pragma unroll
            for (int j = 0; j < 16; j += 2) {
                float p00 = exp2f(s0[j] - mnew), p01 = exp2f(s0[j+1] - mnew);
                float p10 = exp2f(s1[j] - mnew), p11 = exp2f(s1[j+1] - mnew);
                s0[j] = p00; s0[j+1] = p01; s1[j] = p10; s1[j+1] = p11;
                la += p00; lb += p01; lc += p10; ld += p11;
            }
            float ls = (la + lb) + (lc + ld);
            ls += __shfl_xor(ls, 32);
            lrow += ls;

            // ---- O^T += V^T P^T : per k-step m (16 keys), per dh-tile d ----
            __builtin_amdgcn_s_setprio(1);
            #pragma unroll
            for (int m = 0; m < 4; ++m) {
                const int h = m & 1;
                float pa0, pa1, pb0, pb1, pc0, pc1, pd0, pd1;
                if (m < 2) {
                    pa0 = s0[8*h+0]; pa1 = s0[8*h+1]; pc0 = s0[8*h+2]; pc1 = s0[8*h+3];
                    pb0 = s0[8*h+4]; pb1 = s0[8*h+5]; pd0 = s0[8*h+6]; pd1 = s0[8*h+7];
                } else {
                    pa0 = s1[8*h+0]; pa1 = s1[8*h+1]; pc0 = s1[8*h+2]; pc1 = s1[8*h+3];
                    pb0 = s1[8*h+4]; pb1 = s1[8*h+5]; pd0 = s1[8*h+6]; pd1 = s1[8*h+7];
                }
                unsigned int pkA = pack2bf(pa0, pa1), pkC = pack2bf(pc0, pc1);
                unsigned int pkB = pack2bf(pb0, pb1), pkD = pack2bf(pd0, pd1);
                // permlane32_swap: r.x[i]=(i<32)?a[i]:b[i-32], r.y[i]=(i<32)?a[i+32]:b[i]
                u32x2 rAB = __builtin_amdgcn_permlane32_swap(pkA, pkB, false, false);
                u32x2 rCD = __builtin_amdgcn_permlane32_swap(pkC, pkD, false, false);
                u32x4 w;
                w.x = rAB.x;  // e0,e1
                w.y = rCD.x;  // e2,e3
                w.z = rAB.y;  // e4,e5
                w.w = rCD.y;  // e6,e7
                short8 pfrag = __builtin_bit_cast(short8, w);
                #pragma unroll
                for (int d = 0; d < 2; ++d)
                    oacc[d] = __builtin_amdgcn_mfma_f32_32x32x16_bf16(vf[m][d], pfrag, oacc[d], 0, 0, 0);
            }
            __builtin_amdgcn_s_setprio(0);
        }
    }

    // ---- epilogue: lane writes row t = tq, dh varies ----
    const int b = bh >> 4, h = bh & 15;
    const float rinv = 1.0f / lrow;
    unsigned short* orow = O + (size_t)(b * 2048 + tq) * 1024 + h * 64;
    #pragma unroll
    for (int d = 0; d < 2; ++d)
        #pragma unroll
        for (int u2 = 0; u2 < 4; ++u2) {
            int dh0 = d * 32 + u2 * 8 + 4 * hi;
            uint2 w;
            w.x = pack2bf(oacc[d][4*u2+0] * rinv, oacc[d][4*u2+1] * rinv);
            w.y = pack2bf(oacc[d][4*u2+2] * rinv, oacc[d][4*u2+3] * rinv);
            *(uint2*)(orow + dh0) = w;
        }
}

extern "C" void kernel_launch(void* const* d_in, const int* in_sizes, int n_in,
                              void* d_out, int out_size, void* d_ws, size_t ws_size,
                              hipStream_t stream) {
    const float* x     = (const float*)d_in[0];
    const float* Wqkv  = (const float*)d_in[2];
    const float* bqkv  = (const float*)d_in[3];
    const float* Wproj = (const float*)d_in[4];
    const float* bproj = (const float*)d_in[5];
    float* out = (float*)d_out;

    // ws layout (72 MB): Ob aliases xb — xb is dead after gemm<0> (launch 4),
    // Ob is first written by attn (launch 5). Stream order makes this safe.
    char* ws = (char*)d_ws;
    unsigned short* xb  = (unsigned short*)(ws);                    // 16MB [0,16)
    unsigned short* Ob  = (unsigned short*)(ws);                    // alias of xb
    unsigned short* WqT = (unsigned short*)(ws + (16u << 20));      // 6MB  [3072][1024]
    unsigned short* WpT = (unsigned short*)(ws + (22u << 20));      // 2MB  [1024][1024]
    unsigned short* Qb  = (unsigned short*)(ws + (24u << 20));      // 16MB [64][2048][64]
    unsigned short* Kb  = (unsigned short*)(ws + (40u << 20));      // 16MB
    unsigned short* Vt  = (unsigned short*)(ws + (56u << 20));      // 16MB [64][64][2048]

    cvt_bf16_kernel<<<2048, 256, 0, stream>>>(x, xb, (8192 * 1024) / 4);
    transpose_cvt_kernel<<<dim3(96, 32), 256, 0, stream>>>(Wqkv, WqT, 1024, 3072);
    transpose_cvt_kernel<<<dim3(32, 32), 256, 0, stream>>>(Wproj, WpT, 1024, 1024);
    gemm_bt<0><<<dim3(64, 24), 256, 0, stream>>>(xb, WqT, bqkv, Qb, Kb, Vt, nullptr,
                                                 8192, 3072, 1024);
    attn_kernel<<<dim3(8, 64), 512, 0, stream>>>(Qb, Kb, Vt, Ob);
    gemm_bt<1><<<dim3(64, 8), 256, 0, stream>>>(Ob, WpT, bproj, nullptr, nullptr,
                                                nullptr, out, 8192, 1024, 1024);
}

// Round 24
// 196.725 us; speedup vs baseline: 1.1066x; 1.0210x over previous
//
#include <hip/hip_runtime.h>
#include <hip/hip_bf16.h>

typedef __attribute__((ext_vector_type(8))) short short8;
typedef __attribute__((ext_vector_type(4))) float f32x4;
typedef __attribute__((ext_vector_type(16))) float f32x16;
typedef __attribute__((ext_vector_type(4))) unsigned int u32x4;
typedef __attribute__((ext_vector_type(2))) unsigned int u32x2;

#define DEV static __device__ __forceinline__

// hardware bf16 convert (RNE, lowers to v_cvt_pk_bf16_f32)
DEV unsigned short bfc(float f) {
    __bf16 h = (__bf16)f;
    return __builtin_bit_cast(unsigned short, h);
}

DEV unsigned int pack2bf(float lo, float hi) {
    return (unsigned int)bfc(lo) | ((unsigned int)bfc(hi) << 16);
}

DEV void gload16(const void* g, void* l) {
    __builtin_amdgcn_global_load_lds(
        (const __attribute__((address_space(1))) unsigned int*)g,
        (__attribute__((address_space(3))) unsigned int*)l, 16, 0, 0);
}

// ---------------- elementwise f32 -> bf16 ----------------
__global__ void cvt_bf16_kernel(const float* __restrict__ in,
                                unsigned short* __restrict__ out, int n4) {
    int stride = gridDim.x * blockDim.x;
    for (int i = blockIdx.x * blockDim.x + threadIdx.x; i < n4; i += stride) {
        float4 v = reinterpret_cast<const float4*>(in)[i];
        ushort4 o;
        o.x = bfc(v.x); o.y = bfc(v.y); o.z = bfc(v.z); o.w = bfc(v.w);
        reinterpret_cast<ushort4*>(out)[i] = o;
    }
}

// ---------------- W [K][N] f32 -> W^T [N][K] bf16 ----------------
__global__ void transpose_cvt_kernel(const float* __restrict__ in,
                                     unsigned short* __restrict__ out,
                                     int K, int N) {
    __shared__ float tile[32][33];
    int n0 = blockIdx.x * 32, k0 = blockIdx.y * 32;
    int tx = threadIdx.x & 31, ty = threadIdx.x >> 5; // 32 x 8
    #pragma unroll
    for (int i = 0; i < 32; i += 8)
        tile[ty + i][tx] = in[(size_t)(k0 + ty + i) * N + n0 + tx];
    __syncthreads();
    #pragma unroll
    for (int i = 0; i < 32; i += 8)
        out[(size_t)(n0 + ty + i) * K + k0 + tx] = bfc(tile[tx][ty + i]);
}

// ---------------- bf16 GEMM: C[M,N] = A[M,K] * Bt[N,K]^T + bias ----------------
// EPI 0: scatter to Q (pre-scaled by log2e/sqrt(64)), K [BH,T,64], Vt [BH,64,T].
// EPI 1: fp32 out [M,N].
// R23: BK=64 double-buffered 2-phase (16 barriers for K=1024).
// R24: XCD L2-band remap — dispatch id d -> XCD ~ d%8; bm = (d&7)*8+((d>>3)&7)
// gives each XCD an 8-row bm band (A panels 2MB, L2-resident, reused across bn).
// Bijective; per-block work unchanged -> bit-identical output.
template <int EPI>
__global__ __launch_bounds__(256) void gemm_bt(
    const unsigned short* __restrict__ A,
    const unsigned short* __restrict__ Bt,
    const float* __restrict__ bias,
    unsigned short* __restrict__ oQ,
    unsigned short* __restrict__ oK,
    unsigned short* __restrict__ oVt,
    float* __restrict__ oP,
    int M, int N, int K) {
    __shared__ unsigned short As[2 * 128 * 64]; // dbuf, 16KB per buffer
    __shared__ unsigned short Bs[2 * 128 * 64];
    const int tid = threadIdx.x;
    const int wid = tid >> 6, lane = tid & 63;
    const int r = lane & 15, g = lane >> 4;
    const int wm = wid >> 1, wn = wid & 1;

    // ---- XCD band remap (gridDim.x == 64 for both EPI variants) ----
    const int d = blockIdx.y * 64 + blockIdx.x;
    const int bm = (d & 7) * 8 + ((d >> 3) & 7);
    const int bn = d >> 6;

    f32x4 acc[4][4];
    #pragma unroll
    for (int i = 0; i < 4; i++)
        #pragma unroll
        for (int j = 0; j < 4; j++) acc[i][j] = (f32x4)(0.f);

    auto stage = [&](int buf, int k0) {
        // 128x64 tile per matrix = 1024 chunks of 16B; 256 thr x 4 chunks.
        #pragma unroll
        for (int it = 0; it < 4; ++it) {
            int c = it * 256 + tid;          // [0,1024)
            int row = c >> 3, cc = c & 7;    // 8 chunks per 128B row
            int ccs = cc ^ (row & 7);        // swizzled source chunk
            gload16(A + (size_t)(bm * 128 + row) * K + k0 + ccs * 8,
                    (char*)As + buf * 16384 + c * 16);
            gload16(Bt + (size_t)(bn * 128 + row) * K + k0 + ccs * 8,
                    (char*)Bs + buf * 16384 + c * 16);
        }
    };

    const int nk = K >> 6; // 16 for K=1024
    stage(0, 0);
    for (int kt = 0; kt < nk; ++kt) {
        const int cur = kt & 1;
        __syncthreads(); // drains stage(cur)'s vmcnt; fences prior reads of buf cur
        if (kt + 1 < nk) stage(cur ^ 1, (kt + 1) << 6);

        const char* Abase = (const char*)As + cur * 16384;
        const char* Bbase = (const char*)Bs + cur * 16384;
        #pragma unroll
        for (int kk = 0; kk < 2; ++kk) {
            short8 af[4], bfr[4];
            #pragma unroll
            for (int mi = 0; mi < 4; ++mi) {
                int row = wm * 64 + mi * 16 + r;
                af[mi] = *(const short8*)(Abase + row * 128 +
                                          (((kk * 4 + g) ^ (row & 7)) << 4));
            }
            #pragma unroll
            for (int ni = 0; ni < 4; ++ni) {
                int row = wn * 64 + ni * 16 + r;
                bfr[ni] = *(const short8*)(Bbase + row * 128 +
                                           (((kk * 4 + g) ^ (row & 7)) << 4));
            }
            __builtin_amdgcn_s_setprio(1);
            #pragma unroll
            for (int mi = 0; mi < 4; ++mi)
                #pragma unroll
                for (int ni = 0; ni < 4; ++ni)
                    acc[mi][ni] = __builtin_amdgcn_mfma_f32_16x16x32_bf16(
                        af[mi], bfr[ni], acc[mi][ni], 0, 0, 0);
            __builtin_amdgcn_s_setprio(0);
        }
    }

    const float QSCALE = 0.18033688011112042f; // log2(e)/sqrt(64); exp2 domain
    #pragma unroll
    for (int ni = 0; ni < 4; ++ni) {
        int n = bn * 128 + wn * 64 + ni * 16 + r;
        float bb = bias[n];
        #pragma unroll
        for (int mi = 0; mi < 4; ++mi) {
            #pragma unroll
            for (int rr = 0; rr < 4; ++rr) {
                int m = bm * 128 + wm * 64 + mi * 16 + g * 4 + rr;
                float v = acc[mi][ni][rr] + bb;
                if (EPI == 0) {
                    int b = m >> 11, t = m & 2047;
                    int s = n >> 10, hh = (n >> 6) & 15, dh = n & 63;
                    size_t bh = (size_t)(b * 16 + hh);
                    if (s == 0)      oQ[(bh * 2048 + t) * 64 + dh] = bfc(v * QSCALE);
                    else if (s == 1) oK[(bh * 2048 + t) * 64 + dh] = bfc(v);
                    else             oVt[(bh * 64 + dh) * 2048 + t] = bfc(v);
                } else {
                    oP[(size_t)m * N + n] = v;
                }
            }
        }
    }
}

// ---------------- causal flash attention, swapped-QK 32x32 MFMA ----------------
// Q (pre-scaled, exp2 domain): [BH][2048][64] bf16 ; Kb same ; Vt: [BH][64][2048]
// O: [B][2048][1024] bf16. 8 waves x 32 q-rows = 256 rows/block (512 thr).
// KVBLK=128 staged per barrier, two sequential 64-key passes; permlane32_swap
// P-exchange (R20-verified). R24: XCD head-band remap — bh = (d&7)*8+((d>>3)&7)
// puts 8 heads (K/V = 4MB = one L2) per XCD; CU pairs (d, d+256) share bh and
// get qt pairs summing to 7 (perm = 0,1,2,3,7,6,5,4) -> balance preserved.
__global__ __launch_bounds__(512, 2) void attn_kernel(
    const unsigned short* __restrict__ Q,
    const unsigned short* __restrict__ Kb,
    const unsigned short* __restrict__ Vt,
    unsigned short* __restrict__ O) {
    __shared__ unsigned short Ks[2 * 128 * 64]; // dbuf [key][dh], 128B rows, swizzled
    __shared__ unsigned short Vs[2 * 64 * 128]; // dbuf [dh][key], 256B rows, swizzled
    const int tid = threadIdx.x, wid = tid >> 6, lane = tid & 63;
    const int ln31 = lane & 31, hi = lane >> 5;

    // ---- XCD head-band remap (512 blocks; l = by*8+bx) ----
    const int l = blockIdx.y * 8 + blockIdx.x;
    const int bh = (l & 7) * 8 + ((l >> 3) & 7);   // [0,64)
    const int j = l >> 6;                           // [0,8)
    const int qt = (j & 4) ? (7 - (j & 3)) : (j & 3);

    const size_t hoff = (size_t)bh * 2048 * 64;
    const int qrow0 = qt * 256 + wid * 32;   // this wave's first q row
    const int tq = qrow0 + ln31;             // this lane's q row
    const float NEG_INF = -__builtin_inff();

    // Q B-fragments: lane(q=ln31, hi): k = st*16 + hi*8 + e
    short8 qf[4];
    #pragma unroll
    for (int st = 0; st < 4; ++st)
        qf[st] = *(const short8*)(Q + hoff + (size_t)tq * 64 + st * 16 + hi * 8);

    f32x16 oacc[2];
    oacc[0] = (f32x16)(0.f); oacc[1] = (f32x16)(0.f);
    float mrow = NEG_INF, lrow = 0.f;

    const unsigned short* Kh = Kb + hoff;
    const unsigned short* Vh = Vt + hoff;

    auto stage = [&](int buf, int kvb) {
        // 128-key tile: K = 1024 chunks (8/row), V = 1024 chunks (16/row);
        // 512 threads x 2 chunks each per matrix.
        #pragma unroll
        for (int it = 0; it < 2; ++it) {
            int c = it * 512 + tid;            // [0,1024)
            int krow = c >> 3, kcc = c & 7;
            int kccs = kcc ^ (krow & 7);
            gload16(Kh + (size_t)(kvb + krow) * 64 + kccs * 8,
                    (char*)Ks + buf * 16384 + c * 16);
            int vrow = c >> 4, vcc = c & 15;
            int vccs = vcc ^ (vrow & 15);
            gload16(Vh + (size_t)vrow * 2048 + kvb + vccs * 8,
                    (char*)Vs + buf * 16384 + c * 16);
        }
    };

    const int nkv = 2 * qt + 2; // 128-key tiles
    stage(0, 0);
    for (int kv = 0; kv < nkv; ++kv) {
        const int kvb = kv * 128;
        const int cur = kv & 1;
        __syncthreads(); // drains stage(cur)'s vmcnt; fences prior reads of buf cur
        if (kv + 1 < nkv) stage(cur ^ 1, kvb + 128);

        const char* Kbase = (const char*)Ks + cur * 16384;
        const char* Vbase = (const char*)Vs + cur * 16384;

        #pragma unroll
        for (int sub = 0; sub < 2; ++sub) {
            const int kvs = kvb + sub * 64;
            if (kvs > qrow0) continue; // wave-uniform: no unmasked key in subtile

            // ---- S^T = K Q^T : [64 keys x 32 q], two 32-key subtiles ----
            f32x16 s0 = (f32x16)(0.f), s1 = (f32x16)(0.f);
            __builtin_amdgcn_s_setprio(1);
            #pragma unroll
            for (int st = 0; st < 4; ++st) {
                int row0 = sub * 64 + ln31, row1 = sub * 64 + 32 + ln31;
                short8 kf0 = *(const short8*)(Kbase + row0 * 128 +
                                              (((2 * st + hi) ^ (row0 & 7)) << 4));
                short8 kf1 = *(const short8*)(Kbase + row1 * 128 +
                                              (((2 * st + hi) ^ (row1 & 7)) << 4));
                s0 = __builtin_amdgcn_mfma_f32_32x32x16_bf16(kf0, qf[st], s0, 0, 0, 0);
                s1 = __builtin_amdgcn_mfma_f32_32x32x16_bf16(kf1, qf[st], s1, 0, 0, 0);
            }
            __builtin_amdgcn_s_setprio(0);

            // ---- V fragments from LDS, issued BEFORE softmax (latency hides
            // under the exp/max chain). V rows are 256B, 16 chunks/row ----
            short8 vf[4][2];
            #pragma unroll
            for (int m = 0; m < 4; ++m)
                #pragma unroll
                for (int d2 = 0; d2 < 2; ++d2) {
                    int row = d2 * 32 + ln31; // dh
                    int slot = (sub * 8 + 2 * m + hi) ^ (row & 15);
                    vf[m][d2] = *(const short8*)(Vbase + row * 256 + (slot << 4));
                }

            // ---- causal mask (S pre-scaled via Q, exp2 domain) ----
            if (kvs + 63 > qrow0) {
                const int lim = tq - kvs;
                #pragma unroll
                for (int j2 = 0; j2 < 16; ++j2) {
                    int krel = (j2 & 3) + 8 * (j2 >> 2) + 4 * hi;
                    if (krel > lim)      s0[j2] = NEG_INF;
                    if (krel + 32 > lim) s1[j2] = NEG_INF;
                }
            }
            // ---- online softmax (exp2 domain; 4-way interleaved chains) ----
            float ma = fmaxf(s0[0], s0[1]), mb = fmaxf(s0[2], s0[3]);
            float mc = fmaxf(s1[0], s1[1]), md = fmaxf(s1[2], s1[3]);
            #pragma unroll
            for (int j2 = 4; j2 < 16; j2 += 4) {
                ma = fmaxf(ma, fmaxf(s0[j2], s0[j2+1]));
                mb = fmaxf(mb, fmaxf(s0[j2+2], s0[j2+3]));
                mc = fmaxf(mc, fmaxf(s1[j2], s1[j2+1]));
                md = fmaxf(md, fmaxf(s1[j2+2], s1[j2+3]));
            }
            float mloc = fmaxf(fmaxf(ma, mb), fmaxf(mc, md));
            mloc = fmaxf(mloc, __shfl_xor(mloc, 32));
            float mnew = fmaxf(mrow, mloc);
            // bit-exact skip: when all lanes have mloc<=mrow, alpha==1.0 exactly
            if (!__all(mloc <= mrow)) {
                float alpha = exp2f(mrow - mnew);
                lrow *= alpha;
                #pragma unroll
                for (int j2 = 0; j2 < 16; ++j2) { oacc[0][j2] *= alpha; oacc[1][j2] *= alpha; }
            }
            mrow = mnew;
            float la = 0.f, lb = 0.f, lc = 0.f, ld = 0.f;
            #pragma unroll
            for (int j2 = 0; j2 < 16; j2 += 2) {
                float p00 = exp2f(s0[j2] - mnew), p01 = exp2f(s0[j2+1] - mnew);
                float p10 = exp2f(s1[j2] - mnew), p11 = exp2f(s1[j2+1] - mnew);
                s0[j2] = p00; s0[j2+1] = p01; s1[j2] = p10; s1[j2+1] = p11;
                la += p00; lb += p01; lc += p10; ld += p11;
            }
            float ls = (la + lb) + (lc + ld);
            ls += __shfl_xor(ls, 32);
            lrow += ls;

            // ---- O^T += V^T P^T : per k-step m (16 keys), per dh-tile d ----
            __builtin_amdgcn_s_setprio(1);
            #pragma unroll
            for (int m = 0; m < 4; ++m) {
                const int h = m & 1;
                float pa0, pa1, pb0, pb1, pc0, pc1, pd0, pd1;
                if (m < 2) {
                    pa0 = s0[8*h+0]; pa1 = s0[8*h+1]; pc0 = s0[8*h+2]; pc1 = s0[8*h+3];
                    pb0 = s0[8*h+4]; pb1 = s0[8*h+5]; pd0 = s0[8*h+6]; pd1 = s0[8*h+7];
                } else {
                    pa0 = s1[8*h+0]; pa1 = s1[8*h+1]; pc0 = s1[8*h+2]; pc1 = s1[8*h+3];
                    pb0 = s1[8*h+4]; pb1 = s1[8*h+5]; pd0 = s1[8*h+6]; pd1 = s1[8*h+7];
                }
                unsigned int pkA = pack2bf(pa0, pa1), pkC = pack2bf(pc0, pc1);
                unsigned int pkB = pack2bf(pb0, pb1), pkD = pack2bf(pd0, pd1);
                // permlane32_swap: r.x[i]=(i<32)?a[i]:b[i-32], r.y[i]=(i<32)?a[i+32]:b[i]
                u32x2 rAB = __builtin_amdgcn_permlane32_swap(pkA, pkB, false, false);
                u32x2 rCD = __builtin_amdgcn_permlane32_swap(pkC, pkD, false, false);
                u32x4 w;
                w.x = rAB.x;  // e0,e1
                w.y = rCD.x;  // e2,e3
                w.z = rAB.y;  // e4,e5
                w.w = rCD.y;  // e6,e7
                short8 pfrag = __builtin_bit_cast(short8, w);
                #pragma unroll
                for (int d2 = 0; d2 < 2; ++d2)
                    oacc[d2] = __builtin_amdgcn_mfma_f32_32x32x16_bf16(vf[m][d2], pfrag, oacc[d2], 0, 0, 0);
            }
            __builtin_amdgcn_s_setprio(0);
        }
    }

    // ---- epilogue: lane writes row t = tq, dh varies ----
    const int b = bh >> 4, h = bh & 15;
    const float rinv = 1.0f / lrow;
    unsigned short* orow = O + (size_t)(b * 2048 + tq) * 1024 + h * 64;
    #pragma unroll
    for (int d2 = 0; d2 < 2; ++d2)
        #pragma unroll
        for (int u2 = 0; u2 < 4; ++u2) {
            int dh0 = d2 * 32 + u2 * 8 + 4 * hi;
            uint2 w;
            w.x = pack2bf(oacc[d2][4*u2+0] * rinv, oacc[d2][4*u2+1] * rinv);
            w.y = pack2bf(oacc[d2][4*u2+2] * rinv, oacc[d2][4*u2+3] * rinv);
            *(uint2*)(orow + dh0) = w;
        }
}

extern "C" void kernel_launch(void* const* d_in, const int* in_sizes, int n_in,
                              void* d_out, int out_size, void* d_ws, size_t ws_size,
                              hipStream_t stream) {
    const float* x     = (const float*)d_in[0];
    const float* Wqkv  = (const float*)d_in[2];
    const float* bqkv  = (const float*)d_in[3];
    const float* Wproj = (const float*)d_in[4];
    const float* bproj = (const float*)d_in[5];
    float* out = (float*)d_out;

    // ws layout (72 MB): Ob aliases xb — xb is dead after gemm<0> (launch 4),
    // Ob is first written by attn (launch 5). Stream order makes this safe.
    char* ws = (char*)d_ws;
    unsigned short* xb  = (unsigned short*)(ws);                    // 16MB [0,16)
    unsigned short* Ob  = (unsigned short*)(ws);                    // alias of xb
    unsigned short* WqT = (unsigned short*)(ws + (16u << 20));      // 6MB  [3072][1024]
    unsigned short* WpT = (unsigned short*)(ws + (22u << 20));      // 2MB  [1024][1024]
    unsigned short* Qb  = (unsigned short*)(ws + (24u << 20));      // 16MB [64][2048][64]
    unsigned short* Kb  = (unsigned short*)(ws + (40u << 20));      // 16MB
    unsigned short* Vt  = (unsigned short*)(ws + (56u << 20));      // 16MB [64][64][2048]

    cvt_bf16_kernel<<<2048, 256, 0, stream>>>(x, xb, (8192 * 1024) / 4);
    transpose_cvt_kernel<<<dim3(96, 32), 256, 0, stream>>>(Wqkv, WqT, 1024, 3072);
    transpose_cvt_kernel<<<dim3(32, 32), 256, 0, stream>>>(Wproj, WpT, 1024, 1024);
    gemm_bt<0><<<dim3(64, 24), 256, 0, stream>>>(xb, WqT, bqkv, Qb, Kb, Vt, nullptr,
                                                 8192, 3072, 1024);
    attn_kernel<<<dim3(8, 64), 512, 0, stream>>>(Qb, Kb, Vt, Ob);
    gemm_bt<1><<<dim3(64, 8), 256, 0, stream>>>(Ob, WpT, bproj, nullptr, nullptr,
                                                nullptr, out, 8192, 1024, 1024);
}